// Round 1
// baseline (3196.204 us; speedup 1.0000x reference)
//
#include <hip/hip_runtime.h>
#include <math.h>

#define N_NODES 10000
#define N_EDGES 160000
#define LATENT  128
#define NEXP    8
#define EPS     1e-8f
#define ETILE   16

__device__ __forceinline__ float wave_sum64(float x) {
  #pragma unroll
  for (int m = 32; m >= 1; m >>= 1) x += __shfl_xor(x, m, 64);
  return x;
}
__device__ __forceinline__ float group_sum16(float x) {
  #pragma unroll
  for (int m = 8; m >= 1; m >>= 1) x += __shfl_xor(x, m, 64);
  return x;
}

// ---------------- node separable LN ----------------
__global__ __launch_bounds__(256)
void k_node_ln(const float* __restrict__ nf, const float* __restrict__ gn,
               const float* __restrict__ bn, float* __restrict__ nfn) {
  int node = blockIdx.x * 4 + (threadIdx.x >> 6);
  int lane = threadIdx.x & 63;
  const float* row = nf + (size_t)node * 240;
  float* out = nfn + (size_t)node * 240;
  // scalars (64)
  float s = row[lane];
  float mean = wave_sum64(s) * (1.f / 64.f);
  float d = s - mean;
  float var = wave_sum64(d * d) * (1.f / 64.f);
  float rstd = rsqrtf(var + EPS);
  out[lane] = d * rstd * gn[lane] + bn[lane];
  // vectors (32x3 = 96)
  float v0 = row[64 + lane];
  float v1 = (lane < 32) ? row[128 + lane] : 0.f;
  float rsv = rsqrtf(wave_sum64(v0 * v0 + v1 * v1) * (1.f / 96.f) + EPS);
  out[64 + lane] = v0 * rsv * gn[64 + lane / 3];
  if (lane < 32) out[128 + lane] = v1 * rsv * gn[64 + (64 + lane) / 3];
  // tensors (16x5 = 80)
  float t0 = row[160 + lane];
  float t1 = (lane < 16) ? row[224 + lane] : 0.f;
  float rst = rsqrtf(wave_sum64(t0 * t0 + t1 * t1) * (1.f / 80.f) + EPS);
  out[160 + lane] = t0 * rst * gn[96 + lane / 5];
  if (lane < 16) out[224 + lane] = t1 * rst * gn[96 + (64 + lane) / 5];
}

// ---------------- edge kernel ----------------
__global__ __launch_bounds__(256, 2)
void k_edge(const float* __restrict__ latents, const float* __restrict__ ef,
            const float* __restrict__ nfn, const int* __restrict__ eidx,
            const float* __restrict__ ln_ge, const float* __restrict__ ln_be,
            const float* __restrict__ Wg, const float* __restrict__ W0,
            const float* __restrict__ W1, const float* __restrict__ W2,
            const float* __restrict__ P0, const float* __restrict__ b0,
            const float* __restrict__ P1, const float* __restrict__ P2,
            const float* __restrict__ Wenv, const float* __restrict__ benv,
            float* __restrict__ agg) {
  __shared__ __align__(16) float lat[ETILE][128];
  __shared__ __align__(16) float in0[ETILE][192];   // [e][i]        i<192
  __shared__ __align__(16) float in1[ETILE][288];   // [e][m*96+i]   i<96, m<3
  __shared__ __align__(16) float in2[ETILE][240];   // [e][m*48+i]   i<48, m<5
  __shared__ float gates[ETILE][NEXP];
  __shared__ __align__(16) float zbuf[ETILE * 288];
  __shared__ int ecs[ETILE], ens[ETILE];

  const int tid = threadIdx.x;
  const int e0 = blockIdx.x * ETILE;

  if (tid < ETILE) {
    ecs[tid] = eidx[e0 + tid];
    ens[tid] = eidx[N_EDGES + e0 + tid];
  }
  // stage latents (coalesced)
  #pragma unroll
  for (int j = 0; j < 8; ++j) {
    int f = j * 256 + tid;
    int e = f >> 7, c = f & 127;
    lat[e][c] = latents[(size_t)(e0 + e) * LATENT + c];
  }
  __syncthreads();

  const int eg = tid >> 4;   // edge this staging group owns
  const int sl = tid & 15;   // lane within group
  {
    const float* crow = nfn + (size_t)ecs[eg] * 240;
    const float* nrow = nfn + (size_t)ens[eg] * 240;
    const float* erow = ef + (size_t)(e0 + eg) * 240;
    #pragma unroll
    for (int j = 0; j < 15; ++j) {
      int c = j * 16 + sl;
      float cv = crow[c], nv = nrow[c], ev = erow[c];
      if (c < 64) {
        in0[eg][c] = cv; in0[eg][64 + c] = ev; in0[eg][128 + c] = nv;
      } else if (c < 160) {
        int cc = c - 64; int i = cc / 3, m = cc - i * 3;
        in1[eg][m * 96 + i] = cv; in1[eg][m * 96 + 32 + i] = ev; in1[eg][m * 96 + 64 + i] = nv;
      } else {
        int cc = c - 160; int i = cc / 5, m = cc - i * 5;
        in2[eg][m * 48 + i] = cv; in2[eg][m * 48 + 16 + i] = ev; in2[eg][m * 48 + 32 + i] = nv;
      }
    }
  }
  __syncthreads();

  // edge-feature separable LN (in place on e-slots) + softmax gates
  {
    float ssum = 0.f;
    #pragma unroll
    for (int j = 0; j < 4; ++j) ssum += in0[eg][64 + j * 16 + sl];
    ssum = group_sum16(ssum);
    float smean = ssum * (1.f / 64.f);
    float svar = 0.f;
    #pragma unroll
    for (int j = 0; j < 4; ++j) { float x = in0[eg][64 + j * 16 + sl] - smean; svar += x * x; }
    svar = group_sum16(svar) * (1.f / 64.f);
    float srstd = rsqrtf(svar + EPS);

    float vsq = 0.f;
    #pragma unroll
    for (int j = 0; j < 6; ++j) { int idx = j * 16 + sl; int m = idx >> 5, i = idx & 31; float x = in1[eg][m * 96 + 32 + i]; vsq += x * x; }
    vsq = group_sum16(vsq);
    float rsv = rsqrtf(vsq * (1.f / 96.f) + EPS);

    float tsq = 0.f;
    #pragma unroll
    for (int j = 0; j < 5; ++j) { int idx = j * 16 + sl; int m = idx >> 4, i = idx & 15; float x = in2[eg][m * 48 + 16 + i]; tsq += x * x; }
    tsq = group_sum16(tsq);
    float rst = rsqrtf(tsq * (1.f / 80.f) + EPS);

    #pragma unroll
    for (int j = 0; j < 4; ++j) { int c = j * 16 + sl; in0[eg][64 + c] = (in0[eg][64 + c] - smean) * srstd * ln_ge[c] + ln_be[c]; }
    #pragma unroll
    for (int j = 0; j < 6; ++j) { int idx = j * 16 + sl; int m = idx >> 5, i = idx & 31; in1[eg][m * 96 + 32 + i] *= rsv * ln_ge[64 + i]; }
    #pragma unroll
    for (int j = 0; j < 5; ++j) { int idx = j * 16 + sl; int m = idx >> 4, i = idx & 15; in2[eg][m * 48 + 16 + i] *= rst * ln_ge[96 + i]; }

    // gates: softmax(latents @ Wg)
    float ga[NEXP];
    #pragma unroll
    for (int k = 0; k < NEXP; ++k) ga[k] = 0.f;
    #pragma unroll
    for (int j = 0; j < 8; ++j) {
      int c = j * 16 + sl;
      float lv = lat[eg][c];
      #pragma unroll
      for (int k = 0; k < NEXP; ++k) ga[k] += lv * Wg[c * NEXP + k];
    }
    #pragma unroll
    for (int k = 0; k < NEXP; ++k) ga[k] = group_sum16(ga[k]);
    float mx = ga[0];
    #pragma unroll
    for (int k = 1; k < NEXP; ++k) mx = fmaxf(mx, ga[k]);
    float den = 0.f;
    #pragma unroll
    for (int k = 0; k < NEXP; ++k) { ga[k] = expf(ga[k] - mx); den += ga[k]; }
    float inv = 1.f / den;
    if (sl < NEXP) {
      float val = 0.f;
      #pragma unroll
      for (int k = 0; k < NEXP; ++k) if (sl == k) val = ga[k];
      gates[eg][sl] = val * inv;
    }
  }

  // ---- MoE: per-expert prescale z = g*x in LDS, register-accumulated dots ----
  const int eh = tid >> 7;      // which 8 edges this thread covers
  const int uu = tid & 127;     // output-channel index
  const int ebase = eh * 8;
  float acc0[8], acc1[8], acc2[8];
  #pragma unroll
  for (int e = 0; e < 8; ++e) { acc0[e] = 0.f; acc1[e] = 0.f; acc2[e] = 0.f; }

  // l = 0
  for (int k = 0; k < NEXP; ++k) {
    __syncthreads();
    for (int idx = tid; idx < ETILE * 192; idx += 256) {
      int e = idx / 192, c = idx - e * 192;
      zbuf[idx] = gates[e][k] * in0[e][c];
    }
    __syncthreads();
    if (uu < 112) {
      const float* wp = W0 + (size_t)k * 192 * 112 + uu;
      for (int i = 0; i < 192; i += 4) {
        float w0v = wp[(i + 0) * 112];
        float w1v = wp[(i + 1) * 112];
        float w2v = wp[(i + 2) * 112];
        float w3v = wp[(i + 3) * 112];
        #pragma unroll
        for (int e = 0; e < 8; ++e) {
          const float4 zv = *(const float4*)&zbuf[(ebase + e) * 192 + i];
          acc0[e] = fmaf(zv.x, w0v, fmaf(zv.y, w1v, fmaf(zv.z, w2v, fmaf(zv.w, w3v, acc0[e]))));
        }
      }
    }
  }
  // l = 1
  for (int k = 0; k < NEXP; ++k) {
    __syncthreads();
    for (int idx = tid; idx < ETILE * 288; idx += 256) {
      int e = idx / 288, c = idx - e * 288;
      zbuf[idx] = gates[e][k] * in1[e][c];
    }
    __syncthreads();
    if (uu < 96) {
      const int m = uu >> 5, o = uu & 31;
      const float* wp = W1 + (size_t)k * 96 * 32 + o;
      for (int i = 0; i < 96; i += 4) {
        float w0v = wp[(i + 0) * 32];
        float w1v = wp[(i + 1) * 32];
        float w2v = wp[(i + 2) * 32];
        float w3v = wp[(i + 3) * 32];
        #pragma unroll
        for (int e = 0; e < 8; ++e) {
          const float4 zv = *(const float4*)&zbuf[(ebase + e) * 288 + m * 96 + i];
          acc1[e] = fmaf(zv.x, w0v, fmaf(zv.y, w1v, fmaf(zv.z, w2v, fmaf(zv.w, w3v, acc1[e]))));
        }
      }
    }
  }
  // l = 2
  for (int k = 0; k < NEXP; ++k) {
    __syncthreads();
    for (int idx = tid; idx < ETILE * 240; idx += 256) {
      int e = idx / 240, c = idx - e * 240;
      zbuf[idx] = gates[e][k] * in2[e][c];
    }
    __syncthreads();
    if (uu < 80) {
      const int m = uu >> 4, o = uu & 15;
      const float* wp = W2 + (size_t)k * 48 * 16 + o;
      for (int i = 0; i < 48; i += 4) {
        float w0v = wp[(i + 0) * 16];
        float w1v = wp[(i + 1) * 16];
        float w2v = wp[(i + 2) * 16];
        float w3v = wp[(i + 3) * 16];
        #pragma unroll
        for (int e = 0; e < 8; ++e) {
          const float4 zv = *(const float4*)&zbuf[(ebase + e) * 240 + m * 48 + i];
          acc2[e] = fmaf(zv.x, w0v, fmaf(zv.y, w1v, fmaf(zv.z, w2v, fmaf(zv.w, w3v, acc2[e]))));
        }
      }
    }
  }

  // ---- epilogue: nonlinearity -> lin_post -> env weight -> atomic scatter ----
  float* sb  = zbuf;               // [ETILE][64]  silu(s)
  float* g1b = zbuf + ETILE * 64;  // [ETILE][32]
  float* g2b = g1b + ETILE * 32;   // [ETILE][16]
  float* vb  = g2b + ETILE * 16;   // [ETILE][96]  gated v, layout m*32+i
  float* tb  = vb + ETILE * 96;    // [ETILE][80]  gated t, layout m*16+i
  float* wb  = &in0[0][0];         // [ETILE][112] env weights (in0 is dead)

  __syncthreads();
  if (uu < 112) {
    #pragma unroll
    for (int e = 0; e < 8; ++e) {
      int ee = ebase + e;
      float x = acc0[e];
      float sg = 1.f / (1.f + expf(-x));
      if (uu < 64)      sb[ee * 64 + uu] = x * sg;
      else if (uu < 96) g1b[ee * 32 + (uu - 64)] = sg;
      else              g2b[ee * 16 + (uu - 96)] = sg;
    }
  }
  __syncthreads();
  if (uu < 96) {
    const int m = uu >> 5, o = uu & 31;
    #pragma unroll
    for (int e = 0; e < 8; ++e) { int ee = ebase + e; vb[ee * 96 + m * 32 + o] = acc1[e] * g1b[ee * 32 + o]; }
  }
  if (uu < 80) {
    const int m = uu >> 4, o = uu & 15;
    #pragma unroll
    for (int e = 0; e < 8; ++e) { int ee = ebase + e; tb[ee * 80 + m * 16 + o] = acc2[e] * g2b[ee * 16 + o]; }
  }
  // env weights w = latents @ Wenv + benv
  if (uu < 112) {
    float wacc[8];
    #pragma unroll
    for (int e = 0; e < 8; ++e) wacc[e] = benv[uu];
    for (int i = 0; i < 128; i += 4) {
      float w0v = Wenv[(i + 0) * 112 + uu];
      float w1v = Wenv[(i + 1) * 112 + uu];
      float w2v = Wenv[(i + 2) * 112 + uu];
      float w3v = Wenv[(i + 3) * 112 + uu];
      #pragma unroll
      for (int e = 0; e < 8; ++e) {
        const float4 lv = *(const float4*)&lat[ebase + e][i];
        wacc[e] = fmaf(lv.x, w0v, fmaf(lv.y, w1v, fmaf(lv.z, w2v, fmaf(lv.w, w3v, wacc[e]))));
      }
    }
    #pragma unroll
    for (int e = 0; e < 8; ++e) wb[(ebase + e) * 112 + uu] = wacc[e];
  }
  __syncthreads();

  #pragma unroll
  for (int half = 0; half < 2; ++half) {
    if (half == 1 && uu >= 112) break;
    int c = (half == 0) ? uu : 128 + uu;
    float pv[8];
    if (c < 64) {
      const int o = c;
      #pragma unroll
      for (int e = 0; e < 8; ++e) pv[e] = b0[o];
      for (int i = 0; i < 64; ++i) {
        float p = P0[i * 64 + o];
        #pragma unroll
        for (int e = 0; e < 8; ++e) pv[e] = fmaf(sb[(ebase + e) * 64 + i], p, pv[e]);
      }
      #pragma unroll
      for (int e = 0; e < 8; ++e) {
        int ee = ebase + e;
        float msg = pv[e] * wb[ee * 112 + o];
        atomicAdd(&agg[(size_t)ecs[ee] * 240 + c], msg);
      }
    } else if (c < 160) {
      const int vi = c - 64; const int o = vi / 3, m = vi - o * 3;
      #pragma unroll
      for (int e = 0; e < 8; ++e) pv[e] = 0.f;
      for (int i = 0; i < 32; ++i) {
        float p = P1[i * 32 + o];
        #pragma unroll
        for (int e = 0; e < 8; ++e) pv[e] = fmaf(vb[(ebase + e) * 96 + m * 32 + i], p, pv[e]);
      }
      #pragma unroll
      for (int e = 0; e < 8; ++e) {
        int ee = ebase + e;
        float msg = pv[e] * wb[ee * 112 + 64 + o];
        atomicAdd(&agg[(size_t)ecs[ee] * 240 + c], msg);
      }
    } else {
      const int ti = c - 160; const int o = ti / 5, m = ti - o * 5;
      #pragma unroll
      for (int e = 0; e < 8; ++e) pv[e] = 0.f;
      for (int i = 0; i < 16; ++i) {
        float p = P2[i * 16 + o];
        #pragma unroll
        for (int e = 0; e < 8; ++e) pv[e] = fmaf(tb[(ebase + e) * 80 + m * 16 + i], p, pv[e]);
      }
      #pragma unroll
      for (int e = 0; e < 8; ++e) {
        int ee = ebase + e;
        float msg = pv[e] * wb[ee * 112 + 96 + o];
        atomicAdd(&agg[(size_t)ecs[ee] * 240 + c], msg);
      }
    }
  }
}

// ---------------- node residual + species TP ----------------
__global__ __launch_bounds__(256)
void k_node(const float* __restrict__ nf, const float* __restrict__ agg,
            const float* __restrict__ onehot, const float* __restrict__ T0,
            const float* __restrict__ T1, const float* __restrict__ T2,
            float* __restrict__ out) {
  int w = threadIdx.x >> 6;
  int lane = threadIdx.x & 63;
  int node = blockIdx.x * 4 + w;
  __shared__ float buf[4][240];
  const float* nrow = nf + (size_t)node * 240;
  const float* arow = agg + (size_t)node * 240;
  const float c_old = 0.894427190999916f;                 // rsqrt(1.25)
  const float c_new_s = 0.447213595499958f * 0.25f;       // c_new * 16^-0.5
  for (int j = lane; j < 240; j += 64) buf[w][j] = c_old * nrow[j] + c_new_s * arow[j];
  float ohv = (lane < 16) ? onehot[(size_t)node * 16 + lane] : 0.f;
  unsigned long long msk = __ballot(ohv > 0.5f);
  int kk = __ffsll((unsigned long long)msk) - 1;
  __syncthreads();
  #pragma unroll
  for (int rep = 0; rep < 4; ++rep) {
    int c = rep * 64 + lane;
    if (c >= 240) break;
    float d;
    if (c < 64) {
      const float* tp = T0 + (size_t)kk * 64 + c;
      float a = 0.f;
      for (int i = 0; i < 64; ++i) a = fmaf(buf[w][i], tp[(size_t)i * 1024], a);
      d = a;
    } else if (c < 160) {
      int vi = c - 64; int o = vi / 3, m = vi - o * 3;
      const float* tp = T1 + (size_t)kk * 32 + o;
      float a = 0.f;
      for (int i = 0; i < 32; ++i) a = fmaf(buf[w][64 + i * 3 + m], tp[(size_t)i * 512], a);
      d = a;
    } else {
      int ti = c - 160; int o = ti / 5, m = ti - o * 5;
      const float* tp = T2 + (size_t)kk * 16 + o;
      float a = 0.f;
      for (int i = 0; i < 16; ++i) a = fmaf(buf[w][160 + i * 5 + m], tp[(size_t)i * 256], a);
      d = a;
    }
    out[(size_t)node * 240 + c] = buf[w][c] + d;
  }
}

extern "C" void kernel_launch(void* const* d_in, const int* in_sizes, int n_in,
                              void* d_out, int out_size, void* d_ws, size_t ws_size,
                              hipStream_t stream) {
  (void)in_sizes; (void)n_in; (void)out_size; (void)ws_size;
  const float* latents       = (const float*)d_in[0];
  const float* node_features = (const float*)d_in[1];
  const float* edge_features = (const float*)d_in[2];
  const float* node_onehot   = (const float*)d_in[3];
  // d_in[4] edge_vector: unused by the reference
  const float* ln_gn = (const float*)d_in[5];
  const float* ln_bn = (const float*)d_in[6];
  const float* ln_ge = (const float*)d_in[7];
  const float* ln_be = (const float*)d_in[8];
  const float* Wg    = (const float*)d_in[9];
  const float* W0    = (const float*)d_in[10];
  const float* W1    = (const float*)d_in[11];
  const float* W2    = (const float*)d_in[12];
  const float* P0    = (const float*)d_in[13];
  const float* b0    = (const float*)d_in[14];
  const float* P1    = (const float*)d_in[15];
  const float* P2    = (const float*)d_in[16];
  const float* Wenv  = (const float*)d_in[17];
  const float* benv  = (const float*)d_in[18];
  const float* T0    = (const float*)d_in[19];
  const float* T1    = (const float*)d_in[20];
  const float* T2    = (const float*)d_in[21];
  const int*   eidx  = (const int*)d_in[22];
  float* out = (float*)d_out;

  float* nfn = (float*)d_ws;                       // [N_NODES,240] LN'd node feats
  float* agg = nfn + (size_t)N_NODES * 240;        // [N_NODES,240] scatter accum

  hipMemsetAsync(agg, 0, (size_t)N_NODES * 240 * sizeof(float), stream);
  k_node_ln<<<N_NODES / 4, 256, 0, stream>>>(node_features, ln_gn, ln_bn, nfn);
  k_edge<<<N_EDGES / ETILE, 256, 0, stream>>>(latents, edge_features, nfn, eidx,
      ln_ge, ln_be, Wg, W0, W1, W2, P0, b0, P1, P2, Wenv, benv, agg);
  k_node<<<N_NODES / 4, 256, 0, stream>>>(node_features, agg, node_onehot, T0, T1, T2, out);
}

// Round 2
// 705.820 us; speedup vs baseline: 4.5284x; 4.5284x over previous
//
#include <hip/hip_runtime.h>
#include <math.h>

#define N_NODES 10000
#define N_EDGES 160000
#define EPS 1e-8f

typedef __attribute__((ext_vector_type(8))) __bf16 bf16x8;
typedef __attribute__((ext_vector_type(4))) float f32x4;

__device__ __forceinline__ f32x4 MFMA(bf16x8 a, bf16x8 b, f32x4 c){
  return __builtin_amdgcn_mfma_f32_16x16x32_bf16(a, b, c, 0, 0, 0);
}

__device__ __forceinline__ float wave_sum64(float x) {
  #pragma unroll
  for (int m = 32; m >= 1; m >>= 1) x += __shfl_xor(x, m, 64);
  return x;
}
__device__ __forceinline__ float gsum8(float x) {
  x += __shfl_xor(x, 1, 64); x += __shfl_xor(x, 2, 64); x += __shfl_xor(x, 4, 64);
  return x;
}

// LDS layout (units: __bf16 elements within big buffer)
// X0: [0, 12800)        64 rows  x 200   (K=192+8 pad)
// X1: [12800, 32768)    192 rows x 104   (K=96+8)
// X2: [32768, 55808)    320 rows x 72    (K=48 data + 16 zero-pad + 8)
// aliases after phases complete:
// O0: [0, 7680)         64 x 120
// O1: [12800, 20480)    192 x 40
// Wv: [20480, 28160)    64 x 120
// O2: [32768, 45568)    320 x 40
#define SMEM_BYTES 113920   // 111616 + gates 2048 + ecs 256

// swizzled-weight offsets (bf16 elements)
#define W0O 0
#define W1O 196608
#define W2O 221184
#define WEO 229376
#define P0O 245760
#define P1O 249856
#define P2O 250880
#define WTOT 251392

// ---------------- weight pre-swizzle ----------------
__device__ __forceinline__ void prep_seg(int u, const float* __restrict__ src,
                                         __bf16* __restrict__ dst,
                                         int NT, int KS, int Ka, int Na) {
  int per = NT * KS * 512;
  int e = u / per; int r = u - e * per;
  int nt = r / (KS * 512); r -= nt * KS * 512;
  int ks = r >> 9; int li = r & 511;
  int lane = li >> 3, j = li & 7;
  int k = ks * 32 + ((lane >> 4) << 3) + j;
  int n = nt * 16 + (lane & 15);
  float v = (k < Ka && n < Na) ? src[((size_t)e * Ka + k) * Na + n] : 0.f;
  dst[u] = (__bf16)v;
}

__global__ __launch_bounds__(256)
void k_prep(const float* __restrict__ W0, const float* __restrict__ W1,
            const float* __restrict__ W2, const float* __restrict__ We,
            const float* __restrict__ P0, const float* __restrict__ P1,
            const float* __restrict__ P2, __bf16* __restrict__ dst) {
  int t = blockIdx.x * 256 + threadIdx.x;
  if (t >= WTOT) return;
  if      (t < W1O) prep_seg(t - W0O, W0, dst + W0O, 8, 6, 192, 112);
  else if (t < W2O) prep_seg(t - W1O, W1, dst + W1O, 2, 3,  96,  32);
  else if (t < WEO) prep_seg(t - W2O, W2, dst + W2O, 1, 2,  48,  16);
  else if (t < P0O) prep_seg(t - WEO, We, dst + WEO, 8, 4, 128, 112);
  else if (t < P1O) prep_seg(t - P0O, P0, dst + P0O, 4, 2,  64,  64);
  else if (t < P2O) prep_seg(t - P1O, P1, dst + P1O, 2, 1,  32,  32);
  else              prep_seg(t - P2O, P2, dst + P2O, 1, 1,  16,  16);
}

// ---------------- node separable LN ----------------
__global__ __launch_bounds__(256)
void k_node_ln(const float* __restrict__ nf, const float* __restrict__ gn,
               const float* __restrict__ bn, float* __restrict__ nfn) {
  int node = blockIdx.x * 4 + (threadIdx.x >> 6);
  int lane = threadIdx.x & 63;
  const float* row = nf + (size_t)node * 240;
  float* out = nfn + (size_t)node * 240;
  float s = row[lane];
  float mean = wave_sum64(s) * (1.f / 64.f);
  float d = s - mean;
  float var = wave_sum64(d * d) * (1.f / 64.f);
  float rstd = rsqrtf(var + EPS);
  out[lane] = d * rstd * gn[lane] + bn[lane];
  float v0 = row[64 + lane];
  float v1 = (lane < 32) ? row[128 + lane] : 0.f;
  float rsv = rsqrtf(wave_sum64(v0 * v0 + v1 * v1) * (1.f / 96.f) + EPS);
  out[64 + lane] = v0 * rsv * gn[64 + lane / 3];
  if (lane < 32) out[128 + lane] = v1 * rsv * gn[64 + (64 + lane) / 3];
  float t0 = row[160 + lane];
  float t1 = (lane < 16) ? row[224 + lane] : 0.f;
  float rst = rsqrtf(wave_sum64(t0 * t0 + t1 * t1) * (1.f / 80.f) + EPS);
  out[160 + lane] = t0 * rst * gn[96 + lane / 5];
  if (lane < 16) out[224 + lane] = t1 * rst * gn[96 + (64 + lane) / 5];
}

// ---------------- fused edge kernel (MFMA) ----------------
__global__ __launch_bounds__(512, 1)
void k_edge(const float* __restrict__ latents, const float* __restrict__ ef,
            const float* __restrict__ nfn, const int* __restrict__ eidx,
            const float* __restrict__ ln_ge, const float* __restrict__ ln_be,
            const float* __restrict__ Wg, const __bf16* __restrict__ Wsw,
            const float* __restrict__ pb0, const float* __restrict__ benv,
            float* __restrict__ agg) {
  __shared__ __align__(16) char smem[SMEM_BYTES];
  __bf16* SB = (__bf16*)smem;
  float* gatesL = (float*)(smem + 111616);
  int* ecsL = (int*)(smem + 113664);

  const int tid = threadIdx.x;
  const int e0 = blockIdx.x * 64;

  // ================= staging =================
  {
    const int eg = tid >> 3, sl = tid & 7;
    const int ec = eidx[e0 + eg], en = eidx[N_EDGES + e0 + eg];
    if (sl == 0) ecsL[eg] = ec;
    const float* crow = nfn + (size_t)ec * 240;
    const float* nrow = nfn + (size_t)en * 240;
    const float* erow = ef + (size_t)(e0 + eg) * 240;
    float ev[30];
    #pragma unroll
    for (int j = 0; j < 30; ++j) {
      const int c = j * 8 + sl;
      float cv = crow[c], nv = nrow[c];
      ev[j] = erow[c];
      int co, no;
      if (j < 8)       { int b = eg * 200 + c; co = b; no = b + 128; }
      else if (j < 20) { int cc = c - 64; int i = cc / 3, m = cc - 3 * i;
                         int b = 12800 + (m * 64 + eg) * 104 + i; co = b; no = b + 64; }
      else             { int cc = c - 160; int i = cc / 5, m = cc - 5 * i;
                         int b = 32768 + (m * 64 + eg) * 72 + i; co = b; no = b + 32; }
      SB[co] = (__bf16)cv; SB[no] = (__bf16)nv;
    }
    // edge LN stats
    float ssum = 0.f;
    #pragma unroll
    for (int j = 0; j < 8; ++j) ssum += ev[j];
    float mean = gsum8(ssum) * (1.f / 64.f);
    float sv = 0.f;
    #pragma unroll
    for (int j = 0; j < 8; ++j) { float d = ev[j] - mean; sv += d * d; }
    float rstd = rsqrtf(gsum8(sv) * (1.f / 64.f) + EPS);
    float v2 = 0.f;
    #pragma unroll
    for (int j = 8; j < 20; ++j) v2 += ev[j] * ev[j];
    float rsv = rsqrtf(gsum8(v2) * (1.f / 96.f) + EPS);
    float t2 = 0.f;
    #pragma unroll
    for (int j = 20; j < 30; ++j) t2 += ev[j] * ev[j];
    float rst = rsqrtf(gsum8(t2) * (1.f / 80.f) + EPS);
    #pragma unroll
    for (int j = 0; j < 30; ++j) {
      const int c = j * 8 + sl;
      float x = ev[j], y; int eo;
      if (j < 8)       { y = (x - mean) * rstd * ln_ge[c] + ln_be[c]; eo = eg * 200 + c + 64; }
      else if (j < 20) { int cc = c - 64; int i = cc / 3, m = cc - 3 * i;
                         y = x * rsv * ln_ge[64 + i]; eo = 12800 + (m * 64 + eg) * 104 + 32 + i; }
      else             { int cc = c - 160; int i = cc / 5, m = cc - 5 * i;
                         y = x * rst * ln_ge[96 + i]; eo = 32768 + (m * 64 + eg) * 72 + 16 + i; }
      SB[eo] = (__bf16)y;
    }
    // X2 K-pad zeros (cols 48..63)
    for (int z = tid; z < 320 * 16; z += 512)
      SB[32768 + (z >> 4) * 72 + 48 + (z & 15)] = (__bf16)0.f;
    // gates
    float ga[8] = {0.f, 0.f, 0.f, 0.f, 0.f, 0.f, 0.f, 0.f};
    const float* lrow = latents + (size_t)(e0 + eg) * 128;
    #pragma unroll
    for (int j = 0; j < 16; ++j) {
      int c = j * 8 + sl;
      float lv = lrow[c];
      #pragma unroll
      for (int k = 0; k < 8; ++k) ga[k] += lv * Wg[c * 8 + k];
    }
    #pragma unroll
    for (int k = 0; k < 8; ++k) ga[k] = gsum8(ga[k]);
    float mx = ga[0];
    #pragma unroll
    for (int k = 1; k < 8; ++k) mx = fmaxf(mx, ga[k]);
    float den = 0.f;
    #pragma unroll
    for (int k = 0; k < 8; ++k) { ga[k] = expf(ga[k] - mx); den += ga[k]; }
    float val = 0.f;
    #pragma unroll
    for (int k = 0; k < 8; ++k) if (sl == k) val = ga[k];
    gatesL[eg * 8 + sl] = val / den;
  }
  __syncthreads();

  const int w = tid >> 6, lane = tid & 63, kg = lane >> 4, l16 = lane & 15;

  // ================= l0 MoE =================
  {
    const int mtA = (w & 1) * 2, ntA = (w >> 1) * 2;
    f32x4 acc[2][2] = {}; f32x4 D[2][2] = {};
    const __bf16* WB = Wsw + W0O;
    for (int ex = 0; ex < 8; ++ex) {
      #pragma unroll
      for (int ks = 0; ks < 6; ++ks) {
        bf16x8 a0 = *(const bf16x8*)(SB + (mtA * 16 + l16) * 200 + ks * 32 + kg * 8);
        bf16x8 a1 = *(const bf16x8*)(SB + ((mtA + 1) * 16 + l16) * 200 + ks * 32 + kg * 8);
        bf16x8 bA = *(const bf16x8*)(WB + (((ex * 8 + ntA) * 6 + ks) << 9) + lane * 8);
        bf16x8 bB = *(const bf16x8*)(WB + (((ex * 8 + ntA + 1) * 6 + ks) << 9) + lane * 8);
        D[0][0] = MFMA(a0, bA, D[0][0]); D[0][1] = MFMA(a0, bB, D[0][1]);
        D[1][0] = MFMA(a1, bA, D[1][0]); D[1][1] = MFMA(a1, bB, D[1][1]);
      }
      #pragma unroll
      for (int mi = 0; mi < 2; ++mi) {
        #pragma unroll
        for (int jj = 0; jj < 4; ++jj) {
          float g = gatesL[((mtA + mi) * 16 + kg * 4 + jj) * 8 + ex];
          acc[mi][0][jj] += g * D[mi][0][jj]; acc[mi][1][jj] += g * D[mi][1][jj];
          D[mi][0][jj] = 0.f; D[mi][1][jj] = 0.f;
        }
      }
    }
    __syncthreads();   // all waves done reading X0
    #pragma unroll
    for (int mi = 0; mi < 2; ++mi)
      #pragma unroll
      for (int ni = 0; ni < 2; ++ni) {
        int cc = (ntA + ni) * 16 + l16;
        if (cc < 112) {
          #pragma unroll
          for (int jj = 0; jj < 4; ++jj)
            SB[((mtA + mi) * 16 + kg * 4 + jj) * 120 + cc] = (__bf16)acc[mi][ni][jj];
        }
      }
  }

  // ================= l1 MoE =================
  {
    const int ntv = w & 1, mtb = (w >> 1) * 3;
    f32x4 acc[3] = {}; f32x4 D[3] = {};
    const __bf16* WB = Wsw + W1O;
    for (int ex = 0; ex < 8; ++ex) {
      #pragma unroll
      for (int ks = 0; ks < 3; ++ks) {
        bf16x8 b = *(const bf16x8*)(WB + (((ex * 2 + ntv) * 3 + ks) << 9) + lane * 8);
        #pragma unroll
        for (int r = 0; r < 3; ++r) {
          bf16x8 a = *(const bf16x8*)(SB + 12800 + ((mtb + r) * 16 + l16) * 104 + ks * 32 + kg * 8);
          D[r] = MFMA(a, b, D[r]);
        }
      }
      #pragma unroll
      for (int r = 0; r < 3; ++r)
        #pragma unroll
        for (int jj = 0; jj < 4; ++jj) {
          int row = (mtb + r) * 16 + kg * 4 + jj;
          float g = gatesL[(row & 63) * 8 + ex];
          acc[r][jj] += g * D[r][jj]; D[r][jj] = 0.f;
        }
    }
    __syncthreads();   // done reading X1
    #pragma unroll
    for (int r = 0; r < 3; ++r)
      #pragma unroll
      for (int jj = 0; jj < 4; ++jj) {
        int row = (mtb + r) * 16 + kg * 4 + jj;
        SB[12800 + row * 40 + ntv * 16 + l16] = (__bf16)acc[r][jj];
      }
  }

  // ================= l2 MoE =================
  {
    const int mtb = (w < 4) ? w * 3 : 12 + (w - 4) * 2;
    const int mcnt = (w < 4) ? 3 : 2;
    f32x4 acc[3] = {}; f32x4 D[3] = {};
    const __bf16* WB = Wsw + W2O;
    for (int ex = 0; ex < 8; ++ex) {
      #pragma unroll
      for (int ks = 0; ks < 2; ++ks) {
        bf16x8 b = *(const bf16x8*)(WB + ((ex * 2 + ks) << 9) + lane * 8);
        #pragma unroll
        for (int r = 0; r < 3; ++r) if (r < mcnt) {
          bf16x8 a = *(const bf16x8*)(SB + 32768 + ((mtb + r) * 16 + l16) * 72 + ks * 32 + kg * 8);
          D[r] = MFMA(a, b, D[r]);
        }
      }
      #pragma unroll
      for (int r = 0; r < 3; ++r) if (r < mcnt)
        #pragma unroll
        for (int jj = 0; jj < 4; ++jj) {
          int row = (mtb + r) * 16 + kg * 4 + jj;
          float g = gatesL[(row & 63) * 8 + ex];
          acc[r][jj] += g * D[r][jj]; D[r][jj] = 0.f;
        }
    }
    __syncthreads();   // done reading X2
    for (int z = tid; z < 320 * 16; z += 512)
      SB[32768 + (z >> 4) * 40 + 16 + (z & 15)] = (__bf16)0.f;   // O2 K-pad
    #pragma unroll
    for (int r = 0; r < 3; ++r) if (r < mcnt)
      #pragma unroll
      for (int jj = 0; jj < 4; ++jj) {
        int row = (mtb + r) * 16 + kg * 4 + jj;
        SB[32768 + row * 40 + l16] = (__bf16)acc[r][jj];
      }
  }

  // ================= env weights (latents @ Wenv + benv) =================
  {
    const int mtA = (w & 1) * 2, ntA = (w >> 1) * 2;
    f32x4 acc[2][2] = {};
    const __bf16* WB = Wsw + WEO;
    #pragma unroll
    for (int ks = 0; ks < 4; ++ks) {
      bf16x8 a0, a1;
      {
        const float* lp = latents + (size_t)(e0 + mtA * 16 + l16) * 128 + ks * 32 + kg * 8;
        float4 u = *(const float4*)lp; float4 v = *(const float4*)(lp + 4);
        a0[0]=(__bf16)u.x; a0[1]=(__bf16)u.y; a0[2]=(__bf16)u.z; a0[3]=(__bf16)u.w;
        a0[4]=(__bf16)v.x; a0[5]=(__bf16)v.y; a0[6]=(__bf16)v.z; a0[7]=(__bf16)v.w;
      }
      {
        const float* lp = latents + (size_t)(e0 + (mtA + 1) * 16 + l16) * 128 + ks * 32 + kg * 8;
        float4 u = *(const float4*)lp; float4 v = *(const float4*)(lp + 4);
        a1[0]=(__bf16)u.x; a1[1]=(__bf16)u.y; a1[2]=(__bf16)u.z; a1[3]=(__bf16)u.w;
        a1[4]=(__bf16)v.x; a1[5]=(__bf16)v.y; a1[6]=(__bf16)v.z; a1[7]=(__bf16)v.w;
      }
      bf16x8 bA = *(const bf16x8*)(WB + ((ntA * 4 + ks) << 9) + lane * 8);
      bf16x8 bB = *(const bf16x8*)(WB + (((ntA + 1) * 4 + ks) << 9) + lane * 8);
      acc[0][0] = MFMA(a0, bA, acc[0][0]); acc[0][1] = MFMA(a0, bB, acc[0][1]);
      acc[1][0] = MFMA(a1, bA, acc[1][0]); acc[1][1] = MFMA(a1, bB, acc[1][1]);
    }
    #pragma unroll
    for (int mi = 0; mi < 2; ++mi)
      #pragma unroll
      for (int ni = 0; ni < 2; ++ni) {
        int cc = (ntA + ni) * 16 + l16;
        if (cc < 112) {
          float bv = benv[cc];
          #pragma unroll
          for (int jj = 0; jj < 4; ++jj)
            SB[20480 + ((mtA + mi) * 16 + kg * 4 + jj) * 120 + cc] = (__bf16)(acc[mi][ni][jj] + bv);
        }
      }
  }
  __syncthreads();   // all dumps visible

  // ================= gating pass 1: silu / sigmoid on O0 =================
  for (int u = tid; u < 64 * 128; u += 512) {
    int e = u >> 7, c = u & 127;
    if (c < 112) {
      float x = (float)SB[e * 120 + c];
      float sg = 1.f / (1.f + expf(-x));
      SB[e * 120 + c] = (__bf16)(c < 64 ? x * sg : sg);
    }
  }
  __syncthreads();

  // ================= gating pass 2: gate O1 / O2 =================
  for (int u = tid; u < 192 * 32; u += 512) {
    int r = u >> 5, i = u & 31;
    float g = (float)SB[(r & 63) * 120 + 64 + i];
    SB[12800 + r * 40 + i] = (__bf16)((float)SB[12800 + r * 40 + i] * g);
  }
  for (int u = tid; u < 320 * 16; u += 512) {
    int r = u >> 4, i = u & 15;
    float g = (float)SB[(r & 63) * 120 + 96 + i];
    SB[32768 + r * 40 + i] = (__bf16)((float)SB[32768 + r * 40 + i] * g);
  }
  __syncthreads();

  // ================= lin_post s-path + scatter =================
  {
    const int mt = w >> 1, ntb = (w & 1) * 2;
    f32x4 ps[2] = {};
    const __bf16* WB = Wsw + P0O;
    #pragma unroll
    for (int ks = 0; ks < 2; ++ks) {
      bf16x8 a = *(const bf16x8*)(SB + (mt * 16 + l16) * 120 + ks * 32 + kg * 8);
      bf16x8 bA = *(const bf16x8*)(WB + ((ntb * 2 + ks) << 9) + lane * 8);
      bf16x8 bB = *(const bf16x8*)(WB + (((ntb + 1) * 2 + ks) << 9) + lane * 8);
      ps[0] = MFMA(a, bA, ps[0]); ps[1] = MFMA(a, bB, ps[1]);
    }
    #pragma unroll
    for (int ni = 0; ni < 2; ++ni) {
      int cc = (ntb + ni) * 16 + l16;
      float bias = pb0[cc];
      #pragma unroll
      for (int jj = 0; jj < 4; ++jj) {
        int eL = mt * 16 + kg * 4 + jj;
        float msg = (ps[ni][jj] + bias) * (float)SB[20480 + eL * 120 + cc];
        atomicAdd(&agg[(size_t)ecsL[eL] * 240 + cc], msg);
      }
    }
  }
  // ================= lin_post v-path + scatter =================
  {
    const int ntv = w & 1, mtb = (w >> 1) * 3;
    f32x4 pv[3] = {};
    const __bf16* WB = Wsw + P1O;
    bf16x8 b = *(const bf16x8*)(WB + (ntv << 9) + lane * 8);
    #pragma unroll
    for (int r = 0; r < 3; ++r) {
      bf16x8 a = *(const bf16x8*)(SB + 12800 + ((mtb + r) * 16 + l16) * 40 + kg * 8);
      pv[r] = MFMA(a, b, pv[r]);
    }
    #pragma unroll
    for (int r = 0; r < 3; ++r)
      #pragma unroll
      for (int jj = 0; jj < 4; ++jj) {
        int row = (mtb + r) * 16 + kg * 4 + jj;
        int m = row >> 6, eL = row & 63, o = ntv * 16 + l16;
        float msg = pv[r][jj] * (float)SB[20480 + eL * 120 + 64 + o];
        atomicAdd(&agg[(size_t)ecsL[eL] * 240 + 64 + o * 3 + m], msg);
      }
  }
  // ================= lin_post t-path + scatter =================
  {
    const int mtb = (w < 4) ? w * 3 : 12 + (w - 4) * 2;
    const int mcnt = (w < 4) ? 3 : 2;
    f32x4 pt[3] = {};
    const __bf16* WB = Wsw + P2O;
    bf16x8 b = *(const bf16x8*)(WB + lane * 8);
    #pragma unroll
    for (int r = 0; r < 3; ++r) if (r < mcnt) {
      bf16x8 a = *(const bf16x8*)(SB + 32768 + ((mtb + r) * 16 + l16) * 40 + kg * 8);
      pt[r] = MFMA(a, b, pt[r]);
    }
    #pragma unroll
    for (int r = 0; r < 3; ++r) if (r < mcnt)
      #pragma unroll
      for (int jj = 0; jj < 4; ++jj) {
        int row = (mtb + r) * 16 + kg * 4 + jj;
        int m = row >> 6, eL = row & 63, o = l16;
        float msg = pt[r][jj] * (float)SB[20480 + eL * 120 + 96 + o];
        atomicAdd(&agg[(size_t)ecsL[eL] * 240 + 160 + o * 5 + m], msg);
      }
  }
}

// ---------------- node residual + species TP ----------------
__global__ __launch_bounds__(256)
void k_node(const float* __restrict__ nf, const float* __restrict__ agg,
            const float* __restrict__ onehot, const float* __restrict__ T0,
            const float* __restrict__ T1, const float* __restrict__ T2,
            float* __restrict__ out) {
  int w = threadIdx.x >> 6;
  int lane = threadIdx.x & 63;
  int node = blockIdx.x * 4 + w;
  __shared__ float buf[4][240];
  const float* nrow = nf + (size_t)node * 240;
  const float* arow = agg + (size_t)node * 240;
  const float c_old = 0.894427190999916f;
  const float c_new_s = 0.447213595499958f * 0.25f;
  for (int j = lane; j < 240; j += 64) buf[w][j] = c_old * nrow[j] + c_new_s * arow[j];
  float ohv = (lane < 16) ? onehot[(size_t)node * 16 + lane] : 0.f;
  unsigned long long msk = __ballot(ohv > 0.5f);
  int kk = __ffsll((unsigned long long)msk) - 1;
  __syncthreads();
  #pragma unroll
  for (int rep = 0; rep < 4; ++rep) {
    int c = rep * 64 + lane;
    if (c >= 240) break;
    float d;
    if (c < 64) {
      const float* tp = T0 + (size_t)kk * 64 + c;
      float a = 0.f;
      for (int i = 0; i < 64; ++i) a = fmaf(buf[w][i], tp[(size_t)i * 1024], a);
      d = a;
    } else if (c < 160) {
      int vi = c - 64; int o = vi / 3, m = vi - o * 3;
      const float* tp = T1 + (size_t)kk * 32 + o;
      float a = 0.f;
      for (int i = 0; i < 32; ++i) a = fmaf(buf[w][64 + i * 3 + m], tp[(size_t)i * 512], a);
      d = a;
    } else {
      int ti = c - 160; int o = ti / 5, m = ti - o * 5;
      const float* tp = T2 + (size_t)kk * 16 + o;
      float a = 0.f;
      for (int i = 0; i < 16; ++i) a = fmaf(buf[w][160 + i * 5 + m], tp[(size_t)i * 256], a);
      d = a;
    }
    out[(size_t)node * 240 + c] = buf[w][c] + d;
  }
}

extern "C" void kernel_launch(void* const* d_in, const int* in_sizes, int n_in,
                              void* d_out, int out_size, void* d_ws, size_t ws_size,
                              hipStream_t stream) {
  (void)in_sizes; (void)n_in; (void)out_size; (void)ws_size;
  const float* latents       = (const float*)d_in[0];
  const float* node_features = (const float*)d_in[1];
  const float* edge_features = (const float*)d_in[2];
  const float* node_onehot   = (const float*)d_in[3];
  const float* ln_gn = (const float*)d_in[5];
  const float* ln_bn = (const float*)d_in[6];
  const float* ln_ge = (const float*)d_in[7];
  const float* ln_be = (const float*)d_in[8];
  const float* Wg    = (const float*)d_in[9];
  const float* W0    = (const float*)d_in[10];
  const float* W1    = (const float*)d_in[11];
  const float* W2    = (const float*)d_in[12];
  const float* P0    = (const float*)d_in[13];
  const float* b0    = (const float*)d_in[14];
  const float* P1    = (const float*)d_in[15];
  const float* P2    = (const float*)d_in[16];
  const float* Wenv  = (const float*)d_in[17];
  const float* benv  = (const float*)d_in[18];
  const float* T0    = (const float*)d_in[19];
  const float* T1    = (const float*)d_in[20];
  const float* T2    = (const float*)d_in[21];
  const int*   eidx  = (const int*)d_in[22];
  float* out = (float*)d_out;

  float* nfn = (float*)d_ws;                        // [10000,240] f32
  float* agg = nfn + 2400000;                       // [10000,240] f32
  __bf16* Wsw = (__bf16*)((char*)d_ws + 19200000);  // swizzled weights

  hipMemsetAsync(agg, 0, 2400000 * sizeof(float), stream);
  k_prep<<<(WTOT + 255) / 256, 256, 0, stream>>>(W0, W1, W2, Wenv, P0, P1, P2, Wsw);
  k_node_ln<<<N_NODES / 4, 256, 0, stream>>>(node_features, ln_gn, ln_bn, nfn);
  k_edge<<<N_EDGES / 64, 512, 0, stream>>>(latents, edge_features, nfn, eidx,
      ln_ge, ln_be, Wg, Wsw, b0, benv, agg);
  k_node<<<N_NODES / 4, 256, 0, stream>>>(node_features, agg, node_onehot, T0, T1, T2, out);
}

// Round 3
// 652.370 us; speedup vs baseline: 4.8994x; 1.0819x over previous
//
#include <hip/hip_runtime.h>
#include <math.h>

#define N_NODES 10000
#define N_EDGES 160000
#define EPS 1e-8f

typedef __attribute__((ext_vector_type(8))) __bf16 bf16x8;
typedef __attribute__((ext_vector_type(4))) float f32x4;

__device__ __forceinline__ f32x4 MFMA(bf16x8 a, bf16x8 b, f32x4 c){
  return __builtin_amdgcn_mfma_f32_16x16x32_bf16(a, b, c, 0, 0, 0);
}

__device__ __forceinline__ float wave_sum64(float x) {
  #pragma unroll
  for (int m = 32; m >= 1; m >>= 1) x += __shfl_xor(x, m, 64);
  return x;
}
__device__ __forceinline__ float gsum16(float x) {
  x += __shfl_xor(x, 1, 64); x += __shfl_xor(x, 2, 64);
  x += __shfl_xor(x, 4, 64); x += __shfl_xor(x, 8, 64);
  return x;
}

// ---- LDS layout (bf16 element offsets), 32-edge tile ----
// X0: [0, 6400)       32 rows x 200   (c64 | e64 | n64 | pad8)
// X1: [6400, 16384)   96 rows x 104   (c32 | e32 | n32 | pad8), row = m*32+eg
// X2: [16384, 27904)  160 rows x 72   (c16 | e16 | n16 | zero16 | pad8)
// aliases (after source region is dead):
// O0: [0, 3840)       32 x 120
// O1: [6400, 10240)   96 x 40
// Wv: [10240, 14080)  32 x 120
// O2: [16384, 22784)  160 x 40  (cols 16..31 zeroed)
#define X0O 0
#define X1O 6400
#define X2O 16384
#define O0O 0
#define O1O 6400
#define WvO 10240
#define O2O 16384
#define SMEM_BYTES 56960   // 55808 X + 1024 gates + 128 ecs

// swizzled-weight offsets (bf16 elements) -- same as validated round-2 layout
#define W0O 0
#define W1O 196608
#define W2O 221184
#define WEO 229376
#define P0O 245760
#define P1O 249856
#define P2O 250880
#define WTOT 251392

// ---------------- weight pre-swizzle ----------------
__device__ __forceinline__ void prep_seg(int u, const float* __restrict__ src,
                                         __bf16* __restrict__ dst,
                                         int NT, int KS, int Ka, int Na) {
  int per = NT * KS * 512;
  int e = u / per; int r = u - e * per;
  int nt = r / (KS * 512); r -= nt * KS * 512;
  int ks = r >> 9; int li = r & 511;
  int lane = li >> 3, j = li & 7;
  int k = ks * 32 + ((lane >> 4) << 3) + j;
  int n = nt * 16 + (lane & 15);
  float v = (k < Ka && n < Na) ? src[((size_t)e * Ka + k) * Na + n] : 0.f;
  dst[u] = (__bf16)v;
}

__global__ __launch_bounds__(256)
void k_prep(const float* __restrict__ W0, const float* __restrict__ W1,
            const float* __restrict__ W2, const float* __restrict__ We,
            const float* __restrict__ P0, const float* __restrict__ P1,
            const float* __restrict__ P2, __bf16* __restrict__ dst) {
  int t = blockIdx.x * 256 + threadIdx.x;
  if (t >= WTOT) return;
  if      (t < W1O) prep_seg(t - W0O, W0, dst + W0O, 8, 6, 192, 112);
  else if (t < W2O) prep_seg(t - W1O, W1, dst + W1O, 2, 3,  96,  32);
  else if (t < WEO) prep_seg(t - W2O, W2, dst + W2O, 1, 2,  48,  16);
  else if (t < P0O) prep_seg(t - WEO, We, dst + WEO, 8, 4, 128, 112);
  else if (t < P1O) prep_seg(t - P0O, P0, dst + P0O, 4, 2,  64,  64);
  else if (t < P2O) prep_seg(t - P1O, P1, dst + P1O, 2, 1,  32,  32);
  else              prep_seg(t - P2O, P2, dst + P2O, 1, 1,  16,  16);
}

// ---------------- node separable LN -> bf16, fragment-reordered ----------------
// output layout per node row (240 bf16): [0,64) s | 64+m*32+i (v) | 160+m*16+i (t)
__global__ __launch_bounds__(256)
void k_node_ln(const float* __restrict__ nf, const float* __restrict__ gn,
               const float* __restrict__ bn, __bf16* __restrict__ nfn) {
  int node = blockIdx.x * 4 + (threadIdx.x >> 6);
  int lane = threadIdx.x & 63;
  const float* row = nf + (size_t)node * 240;
  __bf16* out = nfn + (size_t)node * 240;
  float s = row[lane];
  float mean = wave_sum64(s) * (1.f / 64.f);
  float d = s - mean;
  float var = wave_sum64(d * d) * (1.f / 64.f);
  float rstd = rsqrtf(var + EPS);
  out[lane] = (__bf16)(d * rstd * gn[lane] + bn[lane]);
  float v0 = row[64 + lane];
  float v1 = (lane < 32) ? row[128 + lane] : 0.f;
  float rsv = rsqrtf(wave_sum64(v0 * v0 + v1 * v1) * (1.f / 96.f) + EPS);
  { int vi = lane; int i = vi / 3, m = vi - 3 * i;
    out[64 + m * 32 + i] = (__bf16)(v0 * rsv * gn[64 + i]); }
  if (lane < 32) { int vi = 64 + lane; int i = vi / 3, m = vi - 3 * i;
    out[64 + m * 32 + i] = (__bf16)(v1 * rsv * gn[64 + i]); }
  float t0 = row[160 + lane];
  float t1 = (lane < 16) ? row[224 + lane] : 0.f;
  float rst = rsqrtf(wave_sum64(t0 * t0 + t1 * t1) * (1.f / 80.f) + EPS);
  { int ti = lane; int i = ti / 5, m = ti - 5 * i;
    out[160 + m * 16 + i] = (__bf16)(t0 * rst * gn[96 + i]); }
  if (lane < 16) { int ti = 64 + lane; int i = ti / 5, m = ti - 5 * i;
    out[160 + m * 16 + i] = (__bf16)(t1 * rst * gn[96 + i]); }
}

// ---------------- fused edge kernel (MFMA), 32 edges/block ----------------
__global__ __launch_bounds__(512, 4)
void k_edge(const float* __restrict__ latents, const float* __restrict__ ef,
            const __bf16* __restrict__ nfn, const int* __restrict__ eidx,
            const float* __restrict__ ln_ge, const float* __restrict__ ln_be,
            const float* __restrict__ Wg, const __bf16* __restrict__ Wsw,
            const float* __restrict__ pb0, const float* __restrict__ benv,
            float* __restrict__ agg) {
  __shared__ __align__(16) char smem[SMEM_BYTES];
  __bf16* SB = (__bf16*)smem;
  float* gatesL = (float*)(smem + 55808);
  int* ecsL = (int*)(smem + 56832);

  const int tid = threadIdx.x;
  const int e0 = blockIdx.x * 32;

  // ================= staging =================
  {
    const int eg = tid >> 4, sl = tid & 15;
    const int ec = eidx[e0 + eg], en = eidx[N_EDGES + e0 + eg];
    if (tid < 32) ecsL[tid] = eidx[e0 + tid];

    // center/neighbor: vectorized bf16 copies from reordered nfn
    #pragma unroll
    for (int j = 0; j < 4; ++j) {
      int ch = j * 16 + sl;
      if (ch >= 60) break;
      int p = ch * 4;
      int dst, eoff;
      if (p < 64)       { dst = X0O + eg * 200 + p; eoff = 64; }
      else if (p < 160) { int q = p - 64; int m = q >> 5, i = q & 31;
                          dst = X1O + (m * 32 + eg) * 104 + i; eoff = 32; }
      else              { int q = p - 160; int m = q >> 4, i = q & 15;
                          dst = X2O + (m * 32 + eg) * 72 + i; eoff = 16; }
      uint2 cv = *(const uint2*)(nfn + (size_t)ec * 240 + p);
      uint2 nv = *(const uint2*)(nfn + (size_t)en * 240 + p);
      *(uint2*)(SB + dst) = cv;
      *(uint2*)(SB + dst + 2 * eoff) = nv;
    }
    // X2 K-pad zeros (cols 48..63)
    for (int z = tid; z < 160 * 4; z += 512) {
      uint2 zz; zz.x = 0; zz.y = 0;
      *(uint2*)(SB + X2O + (z >> 2) * 72 + 48 + (z & 3) * 4) = zz;
    }

    // edge features: f32 load + separable LN + reordered bf16 store
    const float* erow = ef + (size_t)(e0 + eg) * 240;
    float ev[15];
    #pragma unroll
    for (int j = 0; j < 15; ++j) ev[j] = erow[j * 16 + sl];
    float ssum = 0.f;
    #pragma unroll
    for (int j = 0; j < 4; ++j) ssum += ev[j];
    float mean = gsum16(ssum) * (1.f / 64.f);
    float sv = 0.f;
    #pragma unroll
    for (int j = 0; j < 4; ++j) { float dd = ev[j] - mean; sv += dd * dd; }
    float rstd = rsqrtf(gsum16(sv) * (1.f / 64.f) + EPS);
    float v2 = 0.f;
    #pragma unroll
    for (int j = 4; j < 10; ++j) v2 += ev[j] * ev[j];
    float rsv = rsqrtf(gsum16(v2) * (1.f / 96.f) + EPS);
    float t2 = 0.f;
    #pragma unroll
    for (int j = 10; j < 15; ++j) t2 += ev[j] * ev[j];
    float rst = rsqrtf(gsum16(t2) * (1.f / 80.f) + EPS);
    #pragma unroll
    for (int j = 0; j < 15; ++j) {
      const int c = j * 16 + sl;
      float x = ev[j], y; int eo;
      if (j < 4)       { y = (x - mean) * rstd * ln_ge[c] + ln_be[c];
                         eo = X0O + eg * 200 + 64 + c; }
      else if (j < 10) { int cc = c - 64; int i = cc / 3, m = cc - 3 * i;
                         y = x * rsv * ln_ge[64 + i];
                         eo = X1O + (m * 32 + eg) * 104 + 32 + i; }
      else             { int cc = c - 160; int i = cc / 5, m = cc - 5 * i;
                         y = x * rst * ln_ge[96 + i];
                         eo = X2O + (m * 32 + eg) * 72 + 16 + i; }
      SB[eo] = (__bf16)y;
    }

    // gates: softmax(latents @ Wg), contiguous float4 loads
    const float* lrow = latents + (size_t)(e0 + eg) * 128 + sl * 8;
    float4 u4 = *(const float4*)lrow;
    float4 w4 = *(const float4*)(lrow + 4);
    float lv[8] = {u4.x, u4.y, u4.z, u4.w, w4.x, w4.y, w4.z, w4.w};
    float ga[8] = {};
    #pragma unroll
    for (int dd = 0; dd < 8; ++dd) {
      const float* wgr = Wg + (sl * 8 + dd) * 8;
      #pragma unroll
      for (int k = 0; k < 8; ++k) ga[k] += lv[dd] * wgr[k];
    }
    #pragma unroll
    for (int k = 0; k < 8; ++k) ga[k] = gsum16(ga[k]);
    float mx = ga[0];
    #pragma unroll
    for (int k = 1; k < 8; ++k) mx = fmaxf(mx, ga[k]);
    float den = 0.f;
    #pragma unroll
    for (int k = 0; k < 8; ++k) { ga[k] = expf(ga[k] - mx); den += ga[k]; }
    float val = 0.f;
    #pragma unroll
    for (int k = 0; k < 8; ++k) if (sl == k) val = ga[k];
    if (sl < 8) gatesL[eg * 8 + sl] = val / den;
  }
  __syncthreads();

  const int w = tid >> 6, lane = tid & 63, kg = lane >> 4, l16 = lane & 15;

  // ================= l0 MoE (rows 0..31, N=112pad128, K=192) =================
  {
    const int mt = w & 1, ntA = (w >> 1) * 2;
    f32x4 acc[2] = {};
    const __bf16* WB = Wsw + W0O;
    for (int ex = 0; ex < 8; ++ex) {
      f32x4 D[2] = {};
      #pragma unroll
      for (int ks = 0; ks < 6; ++ks) {
        bf16x8 a = *(const bf16x8*)(SB + X0O + (mt * 16 + l16) * 200 + ks * 32 + kg * 8);
        bf16x8 bA = *(const bf16x8*)(WB + (((ex * 8 + ntA) * 6 + ks) << 9) + lane * 8);
        bf16x8 bB = *(const bf16x8*)(WB + (((ex * 8 + ntA + 1) * 6 + ks) << 9) + lane * 8);
        D[0] = MFMA(a, bA, D[0]); D[1] = MFMA(a, bB, D[1]);
      }
      #pragma unroll
      for (int jj = 0; jj < 4; ++jj) {
        float g = gatesL[(mt * 16 + kg * 4 + jj) * 8 + ex];
        acc[0][jj] += g * D[0][jj]; acc[1][jj] += g * D[1][jj];
      }
    }
    __syncthreads();   // all waves done reading X0
    #pragma unroll
    for (int ni = 0; ni < 2; ++ni) {
      int cc = (ntA + ni) * 16 + l16;
      if (cc < 112)
        #pragma unroll
        for (int jj = 0; jj < 4; ++jj)
          SB[O0O + (mt * 16 + kg * 4 + jj) * 120 + cc] = (__bf16)acc[ni][jj];
    }
  }

  // ================= l1 MoE (96 rows, N=32, K=96) =================
  const int nu1 = (w < 4) ? 2 : 1;
  const int mtv0 = w >> 1, ntv = w & 1, mtv1 = (w >> 1) + 4;
  {
    f32x4 acc[2] = {};
    const __bf16* WB = Wsw + W1O;
    for (int ex = 0; ex < 8; ++ex) {
      f32x4 D[2] = {};
      #pragma unroll
      for (int ks = 0; ks < 3; ++ks) {
        bf16x8 b = *(const bf16x8*)(WB + (((ex * 2 + ntv) * 3 + ks) << 9) + lane * 8);
        bf16x8 a0 = *(const bf16x8*)(SB + X1O + (mtv0 * 16 + l16) * 104 + ks * 32 + kg * 8);
        D[0] = MFMA(a0, b, D[0]);
        if (nu1 == 2) {
          bf16x8 a1 = *(const bf16x8*)(SB + X1O + (mtv1 * 16 + l16) * 104 + ks * 32 + kg * 8);
          D[1] = MFMA(a1, b, D[1]);
        }
      }
      #pragma unroll
      for (int jj = 0; jj < 4; ++jj) {
        int r0 = mtv0 * 16 + kg * 4 + jj;
        acc[0][jj] += gatesL[(r0 & 31) * 8 + ex] * D[0][jj];
        if (nu1 == 2) {
          int r1 = mtv1 * 16 + kg * 4 + jj;
          acc[1][jj] += gatesL[(r1 & 31) * 8 + ex] * D[1][jj];
        }
      }
    }
    __syncthreads();   // done reading X1
    #pragma unroll
    for (int jj = 0; jj < 4; ++jj) {
      int r0 = mtv0 * 16 + kg * 4 + jj;
      SB[O1O + r0 * 40 + ntv * 16 + l16] = (__bf16)acc[0][jj];
      if (nu1 == 2) {
        int r1 = mtv1 * 16 + kg * 4 + jj;
        SB[O1O + r1 * 40 + ntv * 16 + l16] = (__bf16)acc[1][jj];
      }
    }
  }

  // ================= l2 MoE (160 rows, N=16, K=48+pad) =================
  const int nu2 = (w < 2) ? 2 : 1;
  const int mt20 = w, mt21 = w + 8;
  {
    f32x4 acc[2] = {};
    const __bf16* WB = Wsw + W2O;
    for (int ex = 0; ex < 8; ++ex) {
      f32x4 D[2] = {};
      #pragma unroll
      for (int ks = 0; ks < 2; ++ks) {
        bf16x8 b = *(const bf16x8*)(WB + ((ex * 2 + ks) << 9) + lane * 8);
        bf16x8 a0 = *(const bf16x8*)(SB + X2O + (mt20 * 16 + l16) * 72 + ks * 32 + kg * 8);
        D[0] = MFMA(a0, b, D[0]);
        if (nu2 == 2) {
          bf16x8 a1 = *(const bf16x8*)(SB + X2O + (mt21 * 16 + l16) * 72 + ks * 32 + kg * 8);
          D[1] = MFMA(a1, b, D[1]);
        }
      }
      #pragma unroll
      for (int jj = 0; jj < 4; ++jj) {
        int r0 = mt20 * 16 + kg * 4 + jj;
        acc[0][jj] += gatesL[(r0 & 31) * 8 + ex] * D[0][jj];
        if (nu2 == 2) {
          int r1 = mt21 * 16 + kg * 4 + jj;
          acc[1][jj] += gatesL[(r1 & 31) * 8 + ex] * D[1][jj];
        }
      }
    }
    __syncthreads();   // done reading X2
    // O2 K-pad zeros (cols 16..31)
    for (int z = tid; z < 160 * 4; z += 512) {
      uint2 zz; zz.x = 0; zz.y = 0;
      *(uint2*)(SB + O2O + (z >> 2) * 40 + 16 + (z & 3) * 4) = zz;
    }
    #pragma unroll
    for (int jj = 0; jj < 4; ++jj) {
      int r0 = mt20 * 16 + kg * 4 + jj;
      SB[O2O + r0 * 40 + l16] = (__bf16)acc[0][jj];
      if (nu2 == 2) {
        int r1 = mt21 * 16 + kg * 4 + jj;
        SB[O2O + r1 * 40 + l16] = (__bf16)acc[1][jj];
      }
    }
  }

  // ================= env weights (latents @ Wenv + benv) =================
  {
    const int mt = w >> 2, np = (w & 3) * 2;
    f32x4 acc[2] = {};
    const __bf16* WB = Wsw + WEO;
    #pragma unroll
    for (int ks = 0; ks < 4; ++ks) {
      bf16x8 a;
      const float* lp = latents + (size_t)(e0 + mt * 16 + l16) * 128 + ks * 32 + kg * 8;
      float4 u4 = *(const float4*)lp; float4 v4 = *(const float4*)(lp + 4);
      a[0]=(__bf16)u4.x; a[1]=(__bf16)u4.y; a[2]=(__bf16)u4.z; a[3]=(__bf16)u4.w;
      a[4]=(__bf16)v4.x; a[5]=(__bf16)v4.y; a[6]=(__bf16)v4.z; a[7]=(__bf16)v4.w;
      bf16x8 bA = *(const bf16x8*)(WB + ((np * 4 + ks) << 9) + lane * 8);
      bf16x8 bB = *(const bf16x8*)(WB + (((np + 1) * 4 + ks) << 9) + lane * 8);
      acc[0] = MFMA(a, bA, acc[0]); acc[1] = MFMA(a, bB, acc[1]);
    }
    #pragma unroll
    for (int ni = 0; ni < 2; ++ni) {
      int cc = (np + ni) * 16 + l16;
      if (cc < 112) {
        float bv = benv[cc];
        #pragma unroll
        for (int jj = 0; jj < 4; ++jj)
          SB[WvO + (mt * 16 + kg * 4 + jj) * 120 + cc] = (__bf16)(acc[ni][jj] + bv);
      }
    }
  }
  __syncthreads();   // O0/O1/O2/Wv dumps + pads all visible

  // ================= gating pass 1: silu / sigmoid on O0 =================
  for (int u = tid; u < 32 * 128; u += 512) {
    int e = u >> 7, c = u & 127;
    if (c < 112) {
      float x = (float)SB[O0O + e * 120 + c];
      float sg = 1.f / (1.f + expf(-x));
      SB[O0O + e * 120 + c] = (__bf16)(c < 64 ? x * sg : sg);
    }
  }
  __syncthreads();

  // ================= gating pass 2: gate O1 / O2 =================
  for (int u = tid; u < 96 * 32; u += 512) {
    int r = u >> 5, i = u & 31;
    float g = (float)SB[O0O + (r & 31) * 120 + 64 + i];
    SB[O1O + r * 40 + i] = (__bf16)((float)SB[O1O + r * 40 + i] * g);
  }
  for (int u = tid; u < 160 * 16; u += 512) {
    int r = u >> 4, i = u & 15;
    float g = (float)SB[O0O + (r & 31) * 120 + 96 + i];
    SB[O2O + r * 40 + i] = (__bf16)((float)SB[O2O + r * 40 + i] * g);
  }
  __syncthreads();

  // ================= lin_post s-path + scatter =================
  {
    const int mt = w & 1, nt = w >> 1;
    f32x4 ps = {};
    const __bf16* WB = Wsw + P0O;
    #pragma unroll
    for (int ks = 0; ks < 2; ++ks) {
      bf16x8 a = *(const bf16x8*)(SB + O0O + (mt * 16 + l16) * 120 + ks * 32 + kg * 8);
      bf16x8 b = *(const bf16x8*)(WB + ((nt * 2 + ks) << 9) + lane * 8);
      ps = MFMA(a, b, ps);
    }
    int cc = nt * 16 + l16;
    float bias = pb0[cc];
    #pragma unroll
    for (int jj = 0; jj < 4; ++jj) {
      int row = mt * 16 + kg * 4 + jj;
      float msg = (ps[jj] + bias) * (float)SB[WvO + row * 120 + cc];
      atomicAdd(&agg[(size_t)ecsL[row] * 240 + cc], msg);
    }
  }
  // ================= lin_post v-path + scatter =================
  {
    f32x4 pv[2] = {};
    const __bf16* WB = Wsw + P1O;
    bf16x8 b = *(const bf16x8*)(WB + (ntv << 9) + lane * 8);
    bf16x8 a0 = *(const bf16x8*)(SB + O1O + (mtv0 * 16 + l16) * 40 + kg * 8);
    pv[0] = MFMA(a0, b, pv[0]);
    if (nu1 == 2) {
      bf16x8 a1 = *(const bf16x8*)(SB + O1O + (mtv1 * 16 + l16) * 40 + kg * 8);
      pv[1] = MFMA(a1, b, pv[1]);
    }
    const int o = ntv * 16 + l16;
    #pragma unroll
    for (int jj = 0; jj < 4; ++jj) {
      int r0 = mtv0 * 16 + kg * 4 + jj;
      int m = r0 >> 5, eL = r0 & 31;
      float msg = pv[0][jj] * (float)SB[WvO + eL * 120 + 64 + o];
      atomicAdd(&agg[(size_t)ecsL[eL] * 240 + 64 + o * 3 + m], msg);
      if (nu1 == 2) {
        int r1 = mtv1 * 16 + kg * 4 + jj;
        int m1 = r1 >> 5, eL1 = r1 & 31;
        float msg1 = pv[1][jj] * (float)SB[WvO + eL1 * 120 + 64 + o];
        atomicAdd(&agg[(size_t)ecsL[eL1] * 240 + 64 + o * 3 + m1], msg1);
      }
    }
  }
  // ================= lin_post t-path + scatter =================
  {
    f32x4 pt[2] = {};
    const __bf16* WB = Wsw + P2O;
    bf16x8 b = *(const bf16x8*)(WB + lane * 8);
    bf16x8 a0 = *(const bf16x8*)(SB + O2O + (mt20 * 16 + l16) * 40 + kg * 8);
    pt[0] = MFMA(a0, b, pt[0]);
    if (nu2 == 2) {
      bf16x8 a1 = *(const bf16x8*)(SB + O2O + (mt21 * 16 + l16) * 40 + kg * 8);
      pt[1] = MFMA(a1, b, pt[1]);
    }
    const int o = l16;
    #pragma unroll
    for (int jj = 0; jj < 4; ++jj) {
      int r0 = mt20 * 16 + kg * 4 + jj;
      int m = r0 >> 5, eL = r0 & 31;
      float msg = pt[0][jj] * (float)SB[WvO + eL * 120 + 96 + o];
      atomicAdd(&agg[(size_t)ecsL[eL] * 240 + 160 + o * 5 + m], msg);
      if (nu2 == 2) {
        int r1 = mt21 * 16 + kg * 4 + jj;
        int m1 = r1 >> 5, eL1 = r1 & 31;
        float msg1 = pt[1][jj] * (float)SB[WvO + eL1 * 120 + 96 + o];
        atomicAdd(&agg[(size_t)ecsL[eL1] * 240 + 160 + o * 5 + m1], msg1);
      }
    }
  }
}

// ---------------- node residual + species TP ----------------
__global__ __launch_bounds__(256)
void k_node(const float* __restrict__ nf, const float* __restrict__ agg,
            const float* __restrict__ onehot, const float* __restrict__ T0,
            const float* __restrict__ T1, const float* __restrict__ T2,
            float* __restrict__ out) {
  int w = threadIdx.x >> 6;
  int lane = threadIdx.x & 63;
  int node = blockIdx.x * 4 + w;
  __shared__ float buf[4][240];
  const float* nrow = nf + (size_t)node * 240;
  const float* arow = agg + (size_t)node * 240;
  const float c_old = 0.894427190999916f;
  const float c_new_s = 0.447213595499958f * 0.25f;
  for (int j = lane; j < 240; j += 64) buf[w][j] = c_old * nrow[j] + c_new_s * arow[j];
  float ohv = (lane < 16) ? onehot[(size_t)node * 16 + lane] : 0.f;
  unsigned long long msk = __ballot(ohv > 0.5f);
  int kk = __ffsll((unsigned long long)msk) - 1;
  __syncthreads();
  #pragma unroll
  for (int rep = 0; rep < 4; ++rep) {
    int c = rep * 64 + lane;
    if (c >= 240) break;
    float d;
    if (c < 64) {
      const float* tp = T0 + (size_t)kk * 64 + c;
      float a = 0.f;
      for (int i = 0; i < 64; ++i) a = fmaf(buf[w][i], tp[(size_t)i * 1024], a);
      d = a;
    } else if (c < 160) {
      int vi = c - 64; int o = vi / 3, m = vi - o * 3;
      const float* tp = T1 + (size_t)kk * 32 + o;
      float a = 0.f;
      for (int i = 0; i < 32; ++i) a = fmaf(buf[w][64 + i * 3 + m], tp[(size_t)i * 512], a);
      d = a;
    } else {
      int ti = c - 160; int o = ti / 5, m = ti - o * 5;
      const float* tp = T2 + (size_t)kk * 16 + o;
      float a = 0.f;
      for (int i = 0; i < 16; ++i) a = fmaf(buf[w][160 + i * 5 + m], tp[(size_t)i * 256], a);
      d = a;
    }
    out[(size_t)node * 240 + c] = buf[w][c] + d;
  }
}

extern "C" void kernel_launch(void* const* d_in, const int* in_sizes, int n_in,
                              void* d_out, int out_size, void* d_ws, size_t ws_size,
                              hipStream_t stream) {
  (void)in_sizes; (void)n_in; (void)out_size; (void)ws_size;
  const float* latents       = (const float*)d_in[0];
  const float* node_features = (const float*)d_in[1];
  const float* edge_features = (const float*)d_in[2];
  const float* node_onehot   = (const float*)d_in[3];
  const float* ln_gn = (const float*)d_in[5];
  const float* ln_bn = (const float*)d_in[6];
  const float* ln_ge = (const float*)d_in[7];
  const float* ln_be = (const float*)d_in[8];
  const float* Wg    = (const float*)d_in[9];
  const float* W0    = (const float*)d_in[10];
  const float* W1    = (const float*)d_in[11];
  const float* W2    = (const float*)d_in[12];
  const float* P0    = (const float*)d_in[13];
  const float* b0    = (const float*)d_in[14];
  const float* P1    = (const float*)d_in[15];
  const float* P2    = (const float*)d_in[16];
  const float* Wenv  = (const float*)d_in[17];
  const float* benv  = (const float*)d_in[18];
  const float* T0    = (const float*)d_in[19];
  const float* T1    = (const float*)d_in[20];
  const float* T2    = (const float*)d_in[21];
  const int*   eidx  = (const int*)d_in[22];
  float* out = (float*)d_out;

  __bf16* nfn = (__bf16*)d_ws;                        // [10000,240] bf16 reordered
  float* agg = (float*)((char*)d_ws + 4800000);       // [10000,240] f32
  __bf16* Wsw = (__bf16*)((char*)d_ws + 14400000);    // swizzled weights

  hipMemsetAsync(agg, 0, 2400000 * sizeof(float), stream);
  k_prep<<<(WTOT + 255) / 256, 256, 0, stream>>>(W0, W1, W2, Wenv, P0, P1, P2, Wsw);
  k_node_ln<<<N_NODES / 4, 256, 0, stream>>>(node_features, ln_gn, ln_bn, nfn);
  k_edge<<<N_EDGES / 32, 512, 0, stream>>>(latents, edge_features, nfn, eidx,
      ln_ge, ln_be, Wg, Wsw, b0, benv, agg);
  k_node<<<N_NODES / 4, 256, 0, stream>>>(node_features, agg, node_onehot, T0, T1, T2, out);
}

// Round 4
// 436.864 us; speedup vs baseline: 7.3162x; 1.4933x over previous
//
#include <hip/hip_runtime.h>
#include <math.h>

#define N_NODES 10000
#define N_EDGES 160000
#define EPS 1e-8f

typedef __attribute__((ext_vector_type(8))) __bf16 bf16x8;
typedef __attribute__((ext_vector_type(4))) float f32x4;

__device__ __forceinline__ f32x4 MFMA(bf16x8 a, bf16x8 b, f32x4 c){
  return __builtin_amdgcn_mfma_f32_16x16x32_bf16(a, b, c, 0, 0, 0);
}

__device__ __forceinline__ float wave_sum64(float x) {
  #pragma unroll
  for (int m = 32; m >= 1; m >>= 1) x += __shfl_xor(x, m, 64);
  return x;
}
__device__ __forceinline__ float gsum16(float x) {
  x += __shfl_xor(x, 1, 64); x += __shfl_xor(x, 2, 64);
  x += __shfl_xor(x, 4, 64); x += __shfl_xor(x, 8, 64);
  return x;
}

// ---- LDS layout (bf16 element offsets), 32-edge tile ----
// X0: [0, 6400)       32 rows x 200
// X1: [6400, 16384)   96 rows x 104   row = m*32+eg
// X2: [16384, 27904)  160 rows x 72   (c16|e16|n16|zero16|pad8)
// Wv: [27904, 31744)  32 x 120        (dedicated, not aliased)
// aliases: O0=X0 (32x120), O1=X1 (96x40), O2=X2 (160x40)
#define X0O 0
#define X1O 6400
#define X2O 16384
#define WvO 27904
#define O0O 0
#define O1O 6400
#define O2O 16384
#define SMEM_BYTES 64640   // 63488 bf16 + 1024 gates + 128 ecs

// swizzled-weight offsets (bf16 elements) -- validated layout
#define W0O 0
#define W1O 196608
#define W2O 221184
#define WEO 229376
#define P0O 245760
#define P1O 249856
#define P2O 250880
#define WTOT 251392

// ---------------- weight pre-swizzle ----------------
__device__ __forceinline__ void prep_seg(int u, const float* __restrict__ src,
                                         __bf16* __restrict__ dst,
                                         int NT, int KS, int Ka, int Na) {
  int per = NT * KS * 512;
  int e = u / per; int r = u - e * per;
  int nt = r / (KS * 512); r -= nt * KS * 512;
  int ks = r >> 9; int li = r & 511;
  int lane = li >> 3, j = li & 7;
  int k = ks * 32 + ((lane >> 4) << 3) + j;
  int n = nt * 16 + (lane & 15);
  float v = (k < Ka && n < Na) ? src[((size_t)e * Ka + k) * Na + n] : 0.f;
  dst[u] = (__bf16)v;
}

__global__ __launch_bounds__(256)
void k_prep(const float* __restrict__ W0, const float* __restrict__ W1,
            const float* __restrict__ W2, const float* __restrict__ We,
            const float* __restrict__ P0, const float* __restrict__ P1,
            const float* __restrict__ P2, __bf16* __restrict__ dst) {
  int t = blockIdx.x * 256 + threadIdx.x;
  if (t >= WTOT) return;
  if      (t < W1O) prep_seg(t - W0O, W0, dst + W0O, 8, 6, 192, 112);
  else if (t < W2O) prep_seg(t - W1O, W1, dst + W1O, 2, 3,  96,  32);
  else if (t < WEO) prep_seg(t - W2O, W2, dst + W2O, 1, 2,  48,  16);
  else if (t < P0O) prep_seg(t - WEO, We, dst + WEO, 8, 4, 128, 112);
  else if (t < P1O) prep_seg(t - P0O, P0, dst + P0O, 4, 2,  64,  64);
  else if (t < P2O) prep_seg(t - P1O, P1, dst + P1O, 2, 1,  32,  32);
  else              prep_seg(t - P2O, P2, dst + P2O, 1, 1,  16,  16);
}

// ---------------- node separable LN -> bf16, fragment-reordered ----------------
__global__ __launch_bounds__(256)
void k_node_ln(const float* __restrict__ nf, const float* __restrict__ gn,
               const float* __restrict__ bn, __bf16* __restrict__ nfn) {
  int node = blockIdx.x * 4 + (threadIdx.x >> 6);
  int lane = threadIdx.x & 63;
  const float* row = nf + (size_t)node * 240;
  __bf16* out = nfn + (size_t)node * 240;
  float s = row[lane];
  float mean = wave_sum64(s) * (1.f / 64.f);
  float d = s - mean;
  float var = wave_sum64(d * d) * (1.f / 64.f);
  float rstd = rsqrtf(var + EPS);
  out[lane] = (__bf16)(d * rstd * gn[lane] + bn[lane]);
  float v0 = row[64 + lane];
  float v1 = (lane < 32) ? row[128 + lane] : 0.f;
  float rsv = rsqrtf(wave_sum64(v0 * v0 + v1 * v1) * (1.f / 96.f) + EPS);
  { int vi = lane; int i = vi / 3, m = vi - 3 * i;
    out[64 + m * 32 + i] = (__bf16)(v0 * rsv * gn[64 + i]); }
  if (lane < 32) { int vi = 64 + lane; int i = vi / 3, m = vi - 3 * i;
    out[64 + m * 32 + i] = (__bf16)(v1 * rsv * gn[64 + i]); }
  float t0 = row[160 + lane];
  float t1 = (lane < 16) ? row[224 + lane] : 0.f;
  float rst = rsqrtf(wave_sum64(t0 * t0 + t1 * t1) * (1.f / 80.f) + EPS);
  { int ti = lane; int i = ti / 5, m = ti - 5 * i;
    out[160 + m * 16 + i] = (__bf16)(t0 * rst * gn[96 + i]); }
  if (lane < 16) { int ti = 64 + lane; int i = ti / 5, m = ti - 5 * i;
    out[160 + m * 16 + i] = (__bf16)(t1 * rst * gn[96 + i]); }
}

// ---------------- fused edge kernel (MFMA), 32 edges/block ----------------
__global__ __launch_bounds__(512, 4)
void k_edge(const float* __restrict__ latents, const float* __restrict__ ef,
            const __bf16* __restrict__ nfn, const int* __restrict__ eidx,
            const float* __restrict__ ln_ge, const float* __restrict__ ln_be,
            const float* __restrict__ Wg, const __bf16* __restrict__ Wsw,
            const float* __restrict__ pb0, const float* __restrict__ benv,
            float* __restrict__ agg) {
  __shared__ __align__(16) char smem[SMEM_BYTES];
  __bf16* SB = (__bf16*)smem;
  float* gatesL = (float*)(smem + 63488);
  int* ecsL = (int*)(smem + 64512);

  const int tid = threadIdx.x;
  const int e0 = blockIdx.x * 32;
  const int w = tid >> 6, lane = tid & 63, kg = lane >> 4, l16 = lane & 15;
  const int eg = tid >> 4, sl = tid & 15;

  // ---- hoisted random gathers (issue before env MFMA phase) ----
  const int ec = eidx[e0 + eg], en = eidx[N_EDGES + e0 + eg];
  if (tid < 32) ecsL[tid] = eidx[e0 + tid];
  uint2 cvr[4], nvr[4];
  #pragma unroll
  for (int j = 0; j < 4; ++j) {
    int ch = j * 16 + sl;
    if (ch < 60) {
      int p = ch * 4;
      cvr[j] = *(const uint2*)(nfn + (size_t)ec * 240 + p);
      nvr[j] = *(const uint2*)(nfn + (size_t)en * 240 + p);
    }
  }

  // ================= env weights (independent MFMA; overlaps gather latency) ===
  {
    const int mt = w >> 2, np = (w & 3) * 2;
    f32x4 acc[2] = {};
    const __bf16* WB = Wsw + WEO;
    #pragma unroll
    for (int ks = 0; ks < 4; ++ks) {
      bf16x8 a;
      const float* lp = latents + (size_t)(e0 + mt * 16 + l16) * 128 + ks * 32 + kg * 8;
      float4 u4 = *(const float4*)lp; float4 v4 = *(const float4*)(lp + 4);
      a[0]=(__bf16)u4.x; a[1]=(__bf16)u4.y; a[2]=(__bf16)u4.z; a[3]=(__bf16)u4.w;
      a[4]=(__bf16)v4.x; a[5]=(__bf16)v4.y; a[6]=(__bf16)v4.z; a[7]=(__bf16)v4.w;
      bf16x8 bA = *(const bf16x8*)(WB + ((np * 4 + ks) << 9) + lane * 8);
      bf16x8 bB = *(const bf16x8*)(WB + (((np + 1) * 4 + ks) << 9) + lane * 8);
      acc[0] = MFMA(a, bA, acc[0]); acc[1] = MFMA(a, bB, acc[1]);
    }
    #pragma unroll
    for (int ni = 0; ni < 2; ++ni) {
      int cc = (np + ni) * 16 + l16;
      if (cc < 112) {
        float bv = benv[cc];
        #pragma unroll
        for (int jj = 0; jj < 4; ++jj)
          SB[WvO + (mt * 16 + kg * 4 + jj) * 120 + cc] = (__bf16)(acc[ni][jj] + bv);
      }
    }
  }

  // ================= staging =================
  {
    // write hoisted gathers
    #pragma unroll
    for (int j = 0; j < 4; ++j) {
      int ch = j * 16 + sl;
      if (ch < 60) {
        int p = ch * 4, dst, eoff;
        if (p < 64)       { dst = X0O + eg * 200 + p; eoff = 64; }
        else if (p < 160) { int q = p - 64; int m = q >> 5, i = q & 31;
                            dst = X1O + (m * 32 + eg) * 104 + i; eoff = 32; }
        else              { int q = p - 160; int m = q >> 4, i = q & 15;
                            dst = X2O + (m * 32 + eg) * 72 + i; eoff = 16; }
        *(uint2*)(SB + dst) = cvr[j];
        *(uint2*)(SB + dst + 2 * eoff) = nvr[j];
      }
    }
    // X2 K-pad zeros (cols 48..63)
    for (int z = tid; z < 160 * 4; z += 512) {
      uint2 zz; zz.x = 0; zz.y = 0;
      *(uint2*)(SB + X2O + (z >> 2) * 72 + 48 + (z & 3) * 4) = zz;
    }

    // edge features: load + separable LN + reordered bf16 store
    const float* erow = ef + (size_t)(e0 + eg) * 240;
    float ev[15];
    #pragma unroll
    for (int j = 0; j < 15; ++j) ev[j] = erow[j * 16 + sl];
    float ssum = 0.f;
    #pragma unroll
    for (int j = 0; j < 4; ++j) ssum += ev[j];
    float mean = gsum16(ssum) * (1.f / 64.f);
    float sv = 0.f;
    #pragma unroll
    for (int j = 0; j < 4; ++j) { float dd = ev[j] - mean; sv += dd * dd; }
    float rstd = rsqrtf(gsum16(sv) * (1.f / 64.f) + EPS);
    float v2 = 0.f;
    #pragma unroll
    for (int j = 4; j < 10; ++j) v2 += ev[j] * ev[j];
    float rsv = rsqrtf(gsum16(v2) * (1.f / 96.f) + EPS);
    float t2 = 0.f;
    #pragma unroll
    for (int j = 10; j < 15; ++j) t2 += ev[j] * ev[j];
    float rst = rsqrtf(gsum16(t2) * (1.f / 80.f) + EPS);
    #pragma unroll
    for (int j = 0; j < 15; ++j) {
      const int c = j * 16 + sl;
      float x = ev[j], y; int eo;
      if (j < 4)       { y = (x - mean) * rstd * ln_ge[c] + ln_be[c];
                         eo = X0O + eg * 200 + 64 + c; }
      else if (j < 10) { int cc = c - 64; int i = cc / 3, m = cc - 3 * i;
                         y = x * rsv * ln_ge[64 + i];
                         eo = X1O + (m * 32 + eg) * 104 + 32 + i; }
      else             { int cc = c - 160; int i = cc / 5, m = cc - 5 * i;
                         y = x * rst * ln_ge[96 + i];
                         eo = X2O + (m * 32 + eg) * 72 + 16 + i; }
      SB[eo] = (__bf16)y;
    }

    // gates: softmax(latents @ Wg)
    const float* lrow = latents + (size_t)(e0 + eg) * 128 + sl * 8;
    float4 u4 = *(const float4*)lrow;
    float4 w4 = *(const float4*)(lrow + 4);
    float lv[8] = {u4.x, u4.y, u4.z, u4.w, w4.x, w4.y, w4.z, w4.w};
    float ga[8] = {};
    #pragma unroll
    for (int dd = 0; dd < 8; ++dd) {
      const float* wgr = Wg + (sl * 8 + dd) * 8;
      #pragma unroll
      for (int k = 0; k < 8; ++k) ga[k] += lv[dd] * wgr[k];
    }
    #pragma unroll
    for (int k = 0; k < 8; ++k) ga[k] = gsum16(ga[k]);
    float mx = ga[0];
    #pragma unroll
    for (int k = 1; k < 8; ++k) mx = fmaxf(mx, ga[k]);
    float den = 0.f;
    #pragma unroll
    for (int k = 0; k < 8; ++k) { ga[k] = expf(ga[k] - mx); den += ga[k]; }
    float val = 0.f;
    #pragma unroll
    for (int k = 0; k < 8; ++k) if (sl == k) val = ga[k];
    if (sl < 8) gatesL[eg * 8 + sl] = val / den;
  }
  __syncthreads();   // bar0: X0/X1/X2/gates ready

  // ================= l0 MoE + fused silu/sigmoid epilogue =================
  {
    const int mt = w & 1, ntA = (w >> 1) * 2;
    f32x4 acc[2] = {};
    const __bf16* WB = Wsw + W0O;
    for (int ex = 0; ex < 8; ++ex) {
      f32x4 D[2] = {};
      #pragma unroll
      for (int ks = 0; ks < 6; ++ks) {
        bf16x8 a = *(const bf16x8*)(SB + X0O + (mt * 16 + l16) * 200 + ks * 32 + kg * 8);
        bf16x8 bA = *(const bf16x8*)(WB + (((ex * 8 + ntA) * 6 + ks) << 9) + lane * 8);
        bf16x8 bB = *(const bf16x8*)(WB + (((ex * 8 + ntA + 1) * 6 + ks) << 9) + lane * 8);
        D[0] = MFMA(a, bA, D[0]); D[1] = MFMA(a, bB, D[1]);
      }
      #pragma unroll
      for (int jj = 0; jj < 4; ++jj) {
        float g = gatesL[(mt * 16 + kg * 4 + jj) * 8 + ex];
        acc[0][jj] += g * D[0][jj]; acc[1][jj] += g * D[1][jj];
      }
    }
    __syncthreads();   // bar1: all waves done reading X0
    #pragma unroll
    for (int ni = 0; ni < 2; ++ni) {
      int cc = (ntA + ni) * 16 + l16;
      if (cc < 112)
        #pragma unroll
        for (int jj = 0; jj < 4; ++jj) {
          float x = acc[ni][jj];
          float sg = 1.f / (1.f + expf(-x));
          float val = (cc < 64) ? x * sg : sg;
          SB[O0O + (mt * 16 + kg * 4 + jj) * 120 + cc] = (__bf16)val;
        }
    }
  }

  // ================= l1 MoE + gated epilogue =================
  const int nu1 = (w < 4) ? 2 : 1;
  const int mtv0 = w >> 1, ntv = w & 1, mtv1 = (w >> 1) + 4;
  {
    f32x4 acc[2] = {};
    const __bf16* WB = Wsw + W1O;
    for (int ex = 0; ex < 8; ++ex) {
      f32x4 D[2] = {};
      #pragma unroll
      for (int ks = 0; ks < 3; ++ks) {
        bf16x8 b = *(const bf16x8*)(WB + (((ex * 2 + ntv) * 3 + ks) << 9) + lane * 8);
        bf16x8 a0 = *(const bf16x8*)(SB + X1O + (mtv0 * 16 + l16) * 104 + ks * 32 + kg * 8);
        D[0] = MFMA(a0, b, D[0]);
        if (nu1 == 2) {
          bf16x8 a1 = *(const bf16x8*)(SB + X1O + (mtv1 * 16 + l16) * 104 + ks * 32 + kg * 8);
          D[1] = MFMA(a1, b, D[1]);
        }
      }
      #pragma unroll
      for (int jj = 0; jj < 4; ++jj) {
        int r0 = mtv0 * 16 + kg * 4 + jj;
        acc[0][jj] += gatesL[(r0 & 31) * 8 + ex] * D[0][jj];
        if (nu1 == 2) {
          int r1 = mtv1 * 16 + kg * 4 + jj;
          acc[1][jj] += gatesL[(r1 & 31) * 8 + ex] * D[1][jj];
        }
      }
    }
    __syncthreads();   // bar2: X1 reads done; O0 stores (pre-bar) now visible
    const int o = ntv * 16 + l16;
    #pragma unroll
    for (int jj = 0; jj < 4; ++jj) {
      int r0 = mtv0 * 16 + kg * 4 + jj;
      float g0 = (float)SB[O0O + (r0 & 31) * 120 + 64 + o];
      SB[O1O + r0 * 40 + o] = (__bf16)(acc[0][jj] * g0);
      if (nu1 == 2) {
        int r1 = mtv1 * 16 + kg * 4 + jj;
        float g1 = (float)SB[O0O + (r1 & 31) * 120 + 64 + o];
        SB[O1O + r1 * 40 + o] = (__bf16)(acc[1][jj] * g1);
      }
    }
  }

  // ================= l2 MoE + gated epilogue =================
  const int nu2 = (w < 2) ? 2 : 1;
  const int mt20 = w, mt21 = w + 8;
  {
    f32x4 acc[2] = {};
    const __bf16* WB = Wsw + W2O;
    for (int ex = 0; ex < 8; ++ex) {
      f32x4 D[2] = {};
      #pragma unroll
      for (int ks = 0; ks < 2; ++ks) {
        bf16x8 b = *(const bf16x8*)(WB + ((ex * 2 + ks) << 9) + lane * 8);
        bf16x8 a0 = *(const bf16x8*)(SB + X2O + (mt20 * 16 + l16) * 72 + ks * 32 + kg * 8);
        D[0] = MFMA(a0, b, D[0]);
        if (nu2 == 2) {
          bf16x8 a1 = *(const bf16x8*)(SB + X2O + (mt21 * 16 + l16) * 72 + ks * 32 + kg * 8);
          D[1] = MFMA(a1, b, D[1]);
        }
      }
      #pragma unroll
      for (int jj = 0; jj < 4; ++jj) {
        int r0 = mt20 * 16 + kg * 4 + jj;
        acc[0][jj] += gatesL[(r0 & 31) * 8 + ex] * D[0][jj];
        if (nu2 == 2) {
          int r1 = mt21 * 16 + kg * 4 + jj;
          acc[1][jj] += gatesL[(r1 & 31) * 8 + ex] * D[1][jj];
        }
      }
    }
    __syncthreads();   // bar3: X2 reads done
    #pragma unroll
    for (int jj = 0; jj < 4; ++jj) {
      int r0 = mt20 * 16 + kg * 4 + jj;
      float g0 = (float)SB[O0O + (r0 & 31) * 120 + 96 + l16];
      SB[O2O + r0 * 40 + l16] = (__bf16)(acc[0][jj] * g0);
      SB[O2O + r0 * 40 + 16 + l16] = (__bf16)0.f;
      if (nu2 == 2) {
        int r1 = mt21 * 16 + kg * 4 + jj;
        float g1 = (float)SB[O0O + (r1 & 31) * 120 + 96 + l16];
        SB[O2O + r1 * 40 + l16] = (__bf16)(acc[1][jj] * g1);
        SB[O2O + r1 * 40 + 16 + l16] = (__bf16)0.f;
      }
    }
  }
  __syncthreads();   // bar4: O0/O1/O2/Wv all visible

  // ================= lin_post s-path + coalesced scatter =================
  {
    const int mt = w & 1, nt = w >> 1;
    f32x4 ps = {};
    const __bf16* WB = Wsw + P0O;
    #pragma unroll
    for (int ks = 0; ks < 2; ++ks) {
      bf16x8 a = *(const bf16x8*)(SB + O0O + (mt * 16 + l16) * 120 + ks * 32 + kg * 8);
      bf16x8 b = *(const bf16x8*)(WB + ((nt * 2 + ks) << 9) + lane * 8);
      ps = MFMA(a, b, ps);
    }
    int cc = nt * 16 + l16;
    float bias = pb0[cc];
    #pragma unroll
    for (int jj = 0; jj < 4; ++jj) {
      int row = mt * 16 + kg * 4 + jj;
      float msg = (ps[jj] + bias) * (float)SB[WvO + row * 120 + cc];
      atomicAdd(&agg[(size_t)ecsL[row] * 240 + cc], msg);
    }
  }
  // ================= lin_post v-path + coalesced scatter =================
  {
    f32x4 pv[2] = {};
    const __bf16* WB = Wsw + P1O;
    bf16x8 b = *(const bf16x8*)(WB + (ntv << 9) + lane * 8);
    bf16x8 a0 = *(const bf16x8*)(SB + O1O + (mtv0 * 16 + l16) * 40 + kg * 8);
    pv[0] = MFMA(a0, b, pv[0]);
    if (nu1 == 2) {
      bf16x8 a1 = *(const bf16x8*)(SB + O1O + (mtv1 * 16 + l16) * 40 + kg * 8);
      pv[1] = MFMA(a1, b, pv[1]);
    }
    const int o = ntv * 16 + l16;
    #pragma unroll
    for (int jj = 0; jj < 4; ++jj) {
      int r0 = mtv0 * 16 + kg * 4 + jj;
      int m = r0 >> 5, eL = r0 & 31;
      float msg = pv[0][jj] * (float)SB[WvO + eL * 120 + 64 + o];
      atomicAdd(&agg[(size_t)ecsL[eL] * 240 + 64 + m * 32 + o], msg);
      if (nu1 == 2) {
        int r1 = mtv1 * 16 + kg * 4 + jj;
        int m1 = r1 >> 5, eL1 = r1 & 31;
        float msg1 = pv[1][jj] * (float)SB[WvO + eL1 * 120 + 64 + o];
        atomicAdd(&agg[(size_t)ecsL[eL1] * 240 + 64 + m1 * 32 + o], msg1);
      }
    }
  }
  // ================= lin_post t-path + coalesced scatter =================
  {
    f32x4 pt[2] = {};
    const __bf16* WB = Wsw + P2O;
    bf16x8 b = *(const bf16x8*)(WB + lane * 8);
    bf16x8 a0 = *(const bf16x8*)(SB + O2O + (mt20 * 16 + l16) * 40 + kg * 8);
    pt[0] = MFMA(a0, b, pt[0]);
    if (nu2 == 2) {
      bf16x8 a1 = *(const bf16x8*)(SB + O2O + (mt21 * 16 + l16) * 40 + kg * 8);
      pt[1] = MFMA(a1, b, pt[1]);
    }
    const int o = l16;
    #pragma unroll
    for (int jj = 0; jj < 4; ++jj) {
      int r0 = mt20 * 16 + kg * 4 + jj;
      int m = r0 >> 5, eL = r0 & 31;
      float msg = pt[0][jj] * (float)SB[WvO + eL * 120 + 96 + o];
      atomicAdd(&agg[(size_t)ecsL[eL] * 240 + 160 + m * 16 + o], msg);
      if (nu2 == 2) {
        int r1 = mt21 * 16 + kg * 4 + jj;
        int m1 = r1 >> 5, eL1 = r1 & 31;
        float msg1 = pt[1][jj] * (float)SB[WvO + eL1 * 120 + 96 + o];
        atomicAdd(&agg[(size_t)ecsL[eL1] * 240 + 160 + m1 * 16 + o], msg1);
      }
    }
  }
}

// ---------------- node residual + species TP (agg in reordered layout) ----------------
__global__ __launch_bounds__(256)
void k_node(const float* __restrict__ nf, const float* __restrict__ agg,
            const float* __restrict__ onehot, const float* __restrict__ T0,
            const float* __restrict__ T1, const float* __restrict__ T2,
            float* __restrict__ out) {
  int w = threadIdx.x >> 6;
  int lane = threadIdx.x & 63;
  int node = blockIdx.x * 4 + w;
  __shared__ float buf[4][240];
  const float* nrow = nf + (size_t)node * 240;
  const float* arow = agg + (size_t)node * 240;
  const float c_old = 0.894427190999916f;
  const float c_new_s = 0.447213595499958f * 0.25f;
  for (int j = lane; j < 240; j += 64) {
    int src;
    if (j < 64) src = j;
    else if (j < 160) { int vi = j - 64; int o = vi / 3, m = vi - 3 * o; src = 64 + m * 32 + o; }
    else              { int ti = j - 160; int o = ti / 5, m = ti - 5 * o; src = 160 + m * 16 + o; }
    buf[w][j] = c_old * nrow[j] + c_new_s * arow[src];
  }
  float ohv = (lane < 16) ? onehot[(size_t)node * 16 + lane] : 0.f;
  unsigned long long msk = __ballot(ohv > 0.5f);
  int kk = __ffsll((unsigned long long)msk) - 1;
  __syncthreads();
  #pragma unroll
  for (int rep = 0; rep < 4; ++rep) {
    int c = rep * 64 + lane;
    if (c >= 240) break;
    float d;
    if (c < 64) {
      const float* tp = T0 + (size_t)kk * 64 + c;
      float a = 0.f;
      for (int i = 0; i < 64; ++i) a = fmaf(buf[w][i], tp[(size_t)i * 1024], a);
      d = a;
    } else if (c < 160) {
      int vi = c - 64; int o = vi / 3, m = vi - o * 3;
      const float* tp = T1 + (size_t)kk * 32 + o;
      float a = 0.f;
      for (int i = 0; i < 32; ++i) a = fmaf(buf[w][64 + i * 3 + m], tp[(size_t)i * 512], a);
      d = a;
    } else {
      int ti = c - 160; int o = ti / 5, m = ti - o * 5;
      const float* tp = T2 + (size_t)kk * 16 + o;
      float a = 0.f;
      for (int i = 0; i < 16; ++i) a = fmaf(buf[w][160 + i * 5 + m], tp[(size_t)i * 256], a);
      d = a;
    }
    out[(size_t)node * 240 + c] = buf[w][c] + d;
  }
}

extern "C" void kernel_launch(void* const* d_in, const int* in_sizes, int n_in,
                              void* d_out, int out_size, void* d_ws, size_t ws_size,
                              hipStream_t stream) {
  (void)in_sizes; (void)n_in; (void)out_size; (void)ws_size;
  const float* latents       = (const float*)d_in[0];
  const float* node_features = (const float*)d_in[1];
  const float* edge_features = (const float*)d_in[2];
  const float* node_onehot   = (const float*)d_in[3];
  const float* ln_gn = (const float*)d_in[5];
  const float* ln_bn = (const float*)d_in[6];
  const float* ln_ge = (const float*)d_in[7];
  const float* ln_be = (const float*)d_in[8];
  const float* Wg    = (const float*)d_in[9];
  const float* W0    = (const float*)d_in[10];
  const float* W1    = (const float*)d_in[11];
  const float* W2    = (const float*)d_in[12];
  const float* P0    = (const float*)d_in[13];
  const float* b0    = (const float*)d_in[14];
  const float* P1    = (const float*)d_in[15];
  const float* P2    = (const float*)d_in[16];
  const float* Wenv  = (const float*)d_in[17];
  const float* benv  = (const float*)d_in[18];
  const float* T0    = (const float*)d_in[19];
  const float* T1    = (const float*)d_in[20];
  const float* T2    = (const float*)d_in[21];
  const int*   eidx  = (const int*)d_in[22];
  float* out = (float*)d_out;

  __bf16* nfn = (__bf16*)d_ws;                        // [10000,240] bf16 reordered
  float* agg = (float*)((char*)d_ws + 4800000);       // [10000,240] f32 (reordered layout)
  __bf16* Wsw = (__bf16*)((char*)d_ws + 14400000);    // swizzled weights

  hipMemsetAsync(agg, 0, 2400000 * sizeof(float), stream);
  k_prep<<<(WTOT + 255) / 256, 256, 0, stream>>>(W0, W1, W2, Wenv, P0, P1, P2, Wsw);
  k_node_ln<<<N_NODES / 4, 256, 0, stream>>>(node_features, ln_gn, ln_bn, nfn);
  k_edge<<<N_EDGES / 32, 512, 0, stream>>>(latents, edge_features, nfn, eidx,
      ln_ge, ln_be, Wg, Wsw, b0, benv, agg);
  k_node<<<N_NODES / 4, 256, 0, stream>>>(node_features, agg, node_onehot, T0, T1, T2, out);
}